// Round 8
// baseline (16288.644 us; speedup 1.0000x reference)
//
#include <hip/hip_runtime.h>
#include <hip/hip_cooperative_groups.h>

#define T_LEN 512
#define B_SZ  128
#define C_IN  128
#define H_SZ  512
#define G4    2048
#define HSLICE 65536   // halves per hF (ld) slice
#define HPAR  262144   // halves per parity (4 slices)
#define XFT   16384    // halves per xF[t]
#define Y0T   131072   // halves per y0F[t]

typedef _Float16 half8 __attribute__((ext_vector_type(8)));
typedef float    float4v __attribute__((ext_vector_type(4)));

#define SCOPE __HIP_MEMORY_SCOPE_AGENT

// Coherent (L2-bypass, L3-backed) helpers — relaxed: no cache flushes.
__device__ __forceinline__ half8 ld_h8c(const _Float16* p) {
  const unsigned long long* q = (const unsigned long long*)p;
  union { unsigned long long u[2]; half8 h; } v;
  v.u[0] = __hip_atomic_load(q,     __ATOMIC_RELAXED, SCOPE);
  v.u[1] = __hip_atomic_load(q + 1, __ATOMIC_RELAXED, SCOPE);
  return v.h;
}
__device__ __forceinline__ void st_u64c(unsigned long long* p, unsigned long long x) {
  __hip_atomic_store(p, x, __ATOMIC_RELAXED, SCOPE);
}

struct PP {
  const _Float16* xF;
  const _Float16 *ew0, *ewr, *ewh, *dw0, *dwr, *dwh;
  const float* bcomb;
  _Float16* y0F;
  _Float16* hst;
  float*    cst;
};

// ---- split-phase grid barrier: 16 leaves x 32 blocks, 8 per-XCD gen mirrors.
// (baseline relaxed protocol — empirically passing; kept byte-identical)
__device__ __forceinline__ void gbar_arrive(unsigned int* bar, int bid, unsigned g) {
  __syncthreads();                       // drains vmcnt: release
  if (threadIdx.x == 0) {
    unsigned old = __hip_atomic_fetch_add(bar + (bid & 15) * 16, 1u, __ATOMIC_RELAXED, SCOPE);
    if (old + 1 == 32u * g) {
      unsigned ro = __hip_atomic_fetch_add(bar + 256, 1u, __ATOMIC_RELAXED, SCOPE);
      if (ro + 1 == 16u * g) {
        #pragma unroll
        for (int i = 0; i < 8; ++i)
          __hip_atomic_store(bar + 320 + i * 16, g, __ATOMIC_RELAXED, SCOPE);
      }
    }
  }
}
__device__ __forceinline__ void gbar_wait(unsigned int* bar, int bid, unsigned g) {
  if (g && threadIdx.x == 0) {
    while (__hip_atomic_load(bar + 320 + (bid & 7) * 16, __ATOMIC_RELAXED, SCOPE) < g)
      __builtin_amdgcn_s_sleep(2);
  }
  __syncthreads();
  asm volatile("" ::: "memory");
}

// frag layout: element (m,k) at (k>>5)*4096 + (m>>4)*512 + ((k>>3)&3)*128 + (m&15)*8 + (k&7)
__device__ __forceinline__ long fragAddr(int m, int k) {
  return (long)(k >> 5) * 4096 + (m >> 4) * 512 + ((k >> 3) & 3) * 128 + (m & 15) * 8 + (k & 7);
}

// Stage 16 gate-cols of [W1;W2] (k-concat) into LDS (normal cached loads).
__device__ __forceinline__ void stage_w2(_Float16* WF,
    const _Float16* W1, long st1, int K1,
    const _Float16* W2, long st2, int K2, int jh0, int tid) {
  const int n8 = ((K1 + K2) >> 5) * 64;
  for (int idx = tid; idx < n8; idx += 256) {
    const int q = idx >> 6, l = idx & 63;
    const int c = l & 15, qd = l >> 4;
    const int j = (c >> 2) * 512 + jh0 + (c & 3);
    const int k = q * 32 + qd * 8;
    const _Float16* src = (k < K1) ? (W1 + (long)j * st1 + k)
                                   : (W2 + (long)j * st2 + (k - K1));
    *(half8*)(WF + (long)idx * 8) = *(const half8*)src;
  }
}

// MFMA over NQ k-chunks, A via normal cached loads.
template <int NQ, int MTS>
__device__ __forceinline__ void mm_norm(float4v (&acc)[MTS][2], const _Float16* WF,
                                        const _Float16* A, int mt0, int kq0, int lane) {
  const _Float16* wl = WF + lane * 8;
  const _Float16* ab = A + (long)mt0 * 512 + lane * 8;
  #pragma unroll
  for (int qq = 0; qq < NQ; ++qq) {
    const half8 bf = *(const half8*)(wl + (long)(kq0 + qq) * 512);
    #pragma unroll
    for (int mt = 0; mt < MTS; ++mt) {
      const half8 af = *(const half8*)(ab + (long)mt * 512 + (long)qq * 4096);
      acc[mt][(kq0 + qq) & 1] =
          __builtin_amdgcn_mfma_f32_16x16x32_f16(af, bf, acc[mt][(kq0 + qq) & 1], 0, 0, 0);
    }
  }
}
// MFMA over NQ k-chunks, A via coherent L3 loads (recurrent h).
template <int NQ, int MTS>
__device__ __forceinline__ void mm_coh(float4v (&acc)[MTS][2], const _Float16* WF,
                                       const _Float16* A, int mt0, int kq0, int lane) {
  const _Float16* wl = WF + lane * 8;
  const _Float16* ab = A + (long)mt0 * 512 + lane * 8;
  #pragma unroll
  for (int qq = 0; qq < NQ; ++qq) {
    const half8 bf = *(const half8*)(wl + (long)(kq0 + qq) * 512);
    #pragma unroll
    for (int mt = 0; mt < MTS; ++mt) {
      const half8 af = ld_h8c(ab + (long)mt * 512 + (long)qq * 4096);
      acc[mt][(kq0 + qq) & 1] =
          __builtin_amdgcn_mfma_f32_16x16x32_f16(af, bf, acc[mt][(kq0 + qq) & 1], 0, 0, 0);
    }
  }
}

// Cell update + packed u64 h-store (atomic) and optional y-store (normal).
template <int MTS>
__device__ __forceinline__ void cell_store(float4v (&acc)[MTS][2], int mt0, int jh0,
    float* c_reg, const float* b4, _Float16* hdst, _Float16* ydst, int ycol0, int lane) {
  const int quad = lane >> 4, jl = lane & 3;
  const bool wr = (lane & 12) == 0;
  const int sbase = (lane & 48) | jl;
  #pragma unroll
  for (int mt = 0; mt < MTS; ++mt) {
    #pragma unroll
    for (int r = 0; r < 4; ++r) {
      const float v = acc[mt][0][r] + acc[mt][1][r];
      const float iv = __shfl(v, sbase);
      const float fv = __shfl(v, sbase | 4);
      const float gv = __shfl(v, sbase | 8);
      const float ov = __shfl(v, sbase | 12);
      float h2 = 0.f;
      if (wr) {
        const float ig = iv + b4[0], fg = fv + b4[1], gg = gv + b4[2], og = ov + b4[3];
        const float si = 1.f / (1.f + __expf(-ig));
        const float sf = 1.f / (1.f + __expf(-fg));
        const float so = 1.f / (1.f + __expf(-og));
        const float eg = __expf(2.f * gg);
        const float tg = (eg - 1.f) / (eg + 1.f);
        const float c2 = sf * c_reg[mt * 4 + r] + si * tg;
        c_reg[mt * 4 + r] = c2;
        const float ec = __expf(2.f * c2);
        h2 = so * (ec - 1.f) / (ec + 1.f);
      }
      union { _Float16 f; unsigned short s; } hb; hb.f = (_Float16)h2;
      int b0 = (int)hb.s;
      int b1 = __shfl_xor(b0, 1);
      int lo = (b0 & 0xffff) | (b1 << 16);
      int hi = __shfl_xor(lo, 2);
      if ((lane & 15) == 0) {
        const unsigned long long u =
            (unsigned long long)(unsigned)lo | ((unsigned long long)(unsigned)hi << 32);
        const int m = (mt0 + mt) * 16 + quad * 4 + r;
        st_u64c((unsigned long long*)(hdst + fragAddr(m, jh0)), u);
        if (ydst) *(unsigned long long*)(ydst + fragAddr(m, ycol0)) = u;
      }
    }
  }
}

// ====================== persistent kernels (baseline fallbacks) =============
__launch_bounds__(256, 2)
__global__ void enc0_persist(PP P, unsigned int* bar) {
  const int bid = blockIdx.x, tid = threadIdx.x;
  const int wave = tid >> 6, lane = tid & 63, quad = lane >> 4;
  __shared__ _Float16 WF[24576];
  const int dir = bid >> 8, mg = (bid >> 7) & 1, rsw = bid & 127;
  const int nidx = (rsw & 7) * 16 + (rsw >> 3);
  const int jh0 = nidx * 4, jh = jh0 + (lane & 3);
  const int mt0 = mg * 4 + wave;

  stage_w2(WF, P.ew0 + (long)dir * G4 * C_IN, C_IN, C_IN,
               P.ewh + (long)dir * G4 * H_SZ, H_SZ, H_SZ, jh0, tid);
  __syncthreads();
  float b4[4], c_reg[4];
  #pragma unroll
  for (int g = 0; g < 4; ++g) b4[g] = P.bcomb[(long)dir * G4 + g * 512 + jh];
  #pragma unroll
  for (int r = 0; r < 4; ++r)
    c_reg[r] = P.cst[(long)dir * HSLICE + (long)(mt0 * 16 + quad * 4 + r) * H_SZ + jh];

  for (int s = 0; s < T_LEN; ++s) {
    const int p = s & 1;
    const int td = dir ? (T_LEN - 1 - s) : s;
    float4v acc[1][2] = {};
    mm_norm<4, 1>(acc, WF, P.xF + (long)td * XFT, mt0, 0, lane);     // overlap zone
    gbar_wait(bar, bid, s);
    mm_coh<16, 1>(acc, WF, P.hst + (long)p * HPAR + (long)dir * HSLICE, mt0, 4, lane);
    cell_store<1>(acc, mt0, jh0, c_reg, b4,
                  P.hst + (long)(1 - p) * HPAR + (long)dir * HSLICE,
                  P.y0F + (long)td * Y0T, dir * 512 + jh0, lane);
    gbar_arrive(bar, bid, s + 1);
  }
  if ((lane & 12) == 0) {
    #pragma unroll
    for (int r = 0; r < 4; ++r)
      P.cst[(long)dir * HSLICE + (long)(mt0 * 16 + quad * 4 + r) * H_SZ + jh] = c_reg[r];
  }
}

__launch_bounds__(256, 2)
__global__ void enc1_persist(PP P, unsigned int* bar) {
  const int bid = blockIdx.x, tid = threadIdx.x;
  const int wave = tid >> 6, lane = tid & 63, quad = lane >> 4;
  __shared__ _Float16 WF[24576];
  const int dir = bid >> 8, mg = (bid >> 7) & 1, rsw = bid & 127;
  const int nidx = (rsw & 7) * 16 + (rsw >> 3);
  const int jh0 = nidx * 4, jh = jh0 + (lane & 3);
  const int mt0 = mg * 4 + wave;
  const int ld = 2 + dir;

  stage_w2(WF, P.ewr + (long)dir * G4 * 1024, 1024, 1024,
               P.ewh + (long)ld * G4 * H_SZ, H_SZ, H_SZ, jh0, tid);
  __syncthreads();
  float b4[4], c_reg[4];
  #pragma unroll
  for (int g = 0; g < 4; ++g) b4[g] = P.bcomb[(long)ld * G4 + g * 512 + jh];
  #pragma unroll
  for (int r = 0; r < 4; ++r)
    c_reg[r] = P.cst[(long)ld * HSLICE + (long)(mt0 * 16 + quad * 4 + r) * H_SZ + jh];

  for (int s = 0; s < T_LEN; ++s) {
    const int p = s & 1;
    const int td = dir ? (T_LEN - 1 - s) : s;
    float4v acc[1][2] = {};
    mm_norm<32, 1>(acc, WF, P.y0F + (long)td * Y0T, mt0, 0, lane);   // overlap zone
    gbar_wait(bar, bid, s);
    mm_coh<16, 1>(acc, WF, P.hst + (long)p * HPAR + (long)ld * HSLICE, mt0, 32, lane);
    cell_store<1>(acc, mt0, jh0, c_reg, b4,
                  P.hst + (long)(1 - p) * HPAR + (long)ld * HSLICE, nullptr, 0, lane);
    gbar_arrive(bar, bid, s + 1);
  }
  if ((lane & 12) == 0) {
    #pragma unroll
    for (int r = 0; r < 4; ++r)
      P.cst[(long)ld * HSLICE + (long)(mt0 * 16 + quad * 4 + r) * H_SZ + jh] = c_reg[r];
  }
}

__launch_bounds__(256, 2)
__global__ void dec_persist(PP P, unsigned int* bar) {
  const int bid = blockIdx.x, tid = threadIdx.x;
  const int wave = tid >> 6, lane = tid & 63, quad = lane >> 4;
  __shared__ _Float16 WF[24576];
  const int q = bid >> 7;              // 0=l0f 1=l0b 2=l1f 3=l1b
  const int layer = q >> 1, dir = q & 1;
  const int rsw = bid & 127;
  const int nidx = (rsw & 7) * 16 + (rsw >> 3);
  const int jh0 = nidx * 4, jh = jh0 + (lane & 3);
  const int mt0 = wave * 2;            // MTS=2
  const int slot = 4 + layer * 2 + dir;
  const int ld = layer * 2 + dir;

  if (layer == 0)
    stage_w2(WF, P.dw0 + (long)dir * G4 * C_IN, C_IN, C_IN,
                 P.dwh + (long)dir * G4 * H_SZ, H_SZ, H_SZ, jh0, tid);
  else
    stage_w2(WF, P.dwr + (long)dir * G4 * 1024, 1024, 1024,
                 P.dwh + (long)ld * G4 * H_SZ, H_SZ, H_SZ, jh0, tid);
  __syncthreads();
  float b4[4], c_reg[8];
  #pragma unroll
  for (int g = 0; g < 4; ++g) b4[g] = P.bcomb[(long)slot * G4 + g * 512 + jh];
  #pragma unroll
  for (int mt = 0; mt < 2; ++mt)
    #pragma unroll
    for (int r = 0; r < 4; ++r)
      c_reg[mt * 4 + r] =
          P.cst[(long)ld * HSLICE + (long)((mt0 + mt) * 16 + quad * 4 + r) * H_SZ + jh];

  for (int s = 0; s <= T_LEN; ++s) {
    const int p = s & 1;
    float4v acc[2][2] = {};
    if (layer == 0 && s < T_LEN)
      mm_norm<4, 2>(acc, WF, P.xF + (long)s * XFT, mt0, 0, lane);    // overlap zone
    gbar_wait(bar, bid, s);
    if (layer == 0) {
      if (s < T_LEN) {
        mm_coh<16, 2>(acc, WF, P.hst + (long)p * HPAR + (long)dir * HSLICE, mt0, 4, lane);
        cell_store<2>(acc, mt0, jh0, c_reg, b4,
                      P.hst + (long)(1 - p) * HPAR + (long)dir * HSLICE, nullptr, 0, lane);
      }
    } else {
      if (s == 0) {
        // seed own h into parity 1 (step s=1 reads parity 1); src from prev kernel.
        if (tid < 64) {
          const long off = (long)(2 + dir) * HSLICE + ((long)rsw * 64 + tid) * 8;
          const unsigned long long* src = (const unsigned long long*)(P.hst + off);
          st_u64c((unsigned long long*)(P.hst + HPAR + off),     src[0]);
          st_u64c((unsigned long long*)(P.hst + HPAR + off) + 1, src[1]);
        }
      } else {
        mm_coh<16, 2>(acc, WF, P.hst + (long)p * HPAR + 0 * HSLICE, mt0, 0, lane);
        mm_coh<16, 2>(acc, WF, P.hst + (long)p * HPAR + 1 * HSLICE, mt0, 16, lane);
        mm_coh<16, 2>(acc, WF, P.hst + (long)p * HPAR + (long)(2 + dir) * HSLICE, mt0, 32, lane);
        cell_store<2>(acc, mt0, jh0, c_reg, b4,
                      P.hst + (long)(1 - p) * HPAR + (long)(2 + dir) * HSLICE, nullptr, 0, lane);
      }
    }
    gbar_arrive(bar, bid, s + 1);
  }
}

// ============== dec 8-wave variant (private helpers, runtime-gated) =========
__device__ __forceinline__ void d8_stage(_Float16* WF,
    const _Float16* W1, long st1, int K1,
    const _Float16* W2, long st2, int K2, int jh0, int tid) {
  const int n8 = ((K1 + K2) >> 5) * 64;
  for (int idx = tid; idx < n8; idx += 512) {
    const int q = idx >> 6, l = idx & 63;
    const int c = l & 15, qd = l >> 4;
    const int j = (c >> 2) * 512 + jh0 + (c & 3);
    const int k = q * 32 + qd * 8;
    const _Float16* src = (k < K1) ? (W1 + (long)j * st1 + k)
                                   : (W2 + (long)j * st2 + (k - K1));
    *(half8*)(WF + (long)idx * 8) = *(const half8*)src;
  }
}
template <int NQ>
__device__ __forceinline__ void d8_mm_norm(float4v (&acc)[2], const _Float16* WF,
                                           const _Float16* A, int mt0, int kq0, int lane) {
  const _Float16* wl = WF + lane * 8;
  const _Float16* ab = A + (long)mt0 * 512 + lane * 8;
  #pragma unroll
  for (int qq = 0; qq < NQ; ++qq) {
    const half8 bf = *(const half8*)(wl + (long)(kq0 + qq) * 512);
    const half8 af = *(const half8*)(ab + (long)qq * 4096);
    acc[(kq0 + qq) & 1] =
        __builtin_amdgcn_mfma_f32_16x16x32_f16(af, bf, acc[(kq0 + qq) & 1], 0, 0, 0);
  }
}
template <int NQ>
__device__ __forceinline__ void d8_mm_coh(float4v (&acc)[2], const _Float16* WF,
                                          const _Float16* A, int mt0, int kq0, int lane) {
  const _Float16* wl = WF + lane * 8;
  const _Float16* ab = A + (long)mt0 * 512 + lane * 8;
  #pragma unroll
  for (int qq = 0; qq < NQ; ++qq) {
    const half8 bf = *(const half8*)(wl + (long)(kq0 + qq) * 512);
    const half8 af = ld_h8c(ab + (long)qq * 4096);
    acc[(kq0 + qq) & 1] =
        __builtin_amdgcn_mfma_f32_16x16x32_f16(af, bf, acc[(kq0 + qq) & 1], 0, 0, 0);
  }
}
__device__ __forceinline__ void d8_cell(float4v (&acc)[2], int mt0, int jh0,
    float* c_reg, const float* b4, _Float16* hdst, int lane) {
  const int quad = lane >> 4, jl = lane & 3;
  const bool wr = (lane & 12) == 0;
  const int sbase = (lane & 48) | jl;
  #pragma unroll
  for (int r = 0; r < 4; ++r) {
    const float v = acc[0][r] + acc[1][r];
    const float iv = __shfl(v, sbase);
    const float fv = __shfl(v, sbase | 4);
    const float gv = __shfl(v, sbase | 8);
    const float ov = __shfl(v, sbase | 12);
    float h2 = 0.f;
    if (wr) {
      const float ig = iv + b4[0], fg = fv + b4[1], gg = gv + b4[2], og = ov + b4[3];
      const float si = 1.f / (1.f + __expf(-ig));
      const float sf = 1.f / (1.f + __expf(-fg));
      const float so = 1.f / (1.f + __expf(-og));
      const float eg = __expf(2.f * gg);
      const float tg = (eg - 1.f) / (eg + 1.f);
      const float c2 = sf * c_reg[r] + si * tg;
      c_reg[r] = c2;
      const float ec = __expf(2.f * c2);
      h2 = so * (ec - 1.f) / (ec + 1.f);
    }
    union { _Float16 f; unsigned short s; } hb; hb.f = (_Float16)h2;
    int b0 = (int)hb.s;
    int b1 = __shfl_xor(b0, 1);
    int lo = (b0 & 0xffff) | (b1 << 16);
    int hi = __shfl_xor(lo, 2);
    if ((lane & 15) == 0) {
      const unsigned long long u =
          (unsigned long long)(unsigned)lo | ((unsigned long long)(unsigned)hi << 32);
      const int m = mt0 * 16 + quad * 4 + r;
      st_u64c((unsigned long long*)(hdst + fragAddr(m, jh0)), u);
    }
  }
}

__launch_bounds__(512, 4)
__global__ void dec_persist8(PP P, unsigned int* bar) {
  const int bid = blockIdx.x, tid = threadIdx.x;
  const int wave = tid >> 6, lane = tid & 63, quad = lane >> 4;
  __shared__ _Float16 WF[24576];
  const int q = bid >> 7;              // 0=l0f 1=l0b 2=l1f 3=l1b
  const int layer = q >> 1, dir = q & 1;
  const int rsw = bid & 127;
  const int nidx = (rsw & 7) * 16 + (rsw >> 3);
  const int jh0 = nidx * 4, jh = jh0 + (lane & 3);
  const int mt0 = wave;                // 8 waves, one 16-row m-tile each
  const int slot = 4 + layer * 2 + dir;
  const int ld = layer * 2 + dir;

  if (layer == 0)
    d8_stage(WF, P.dw0 + (long)dir * G4 * C_IN, C_IN, C_IN,
                 P.dwh + (long)dir * G4 * H_SZ, H_SZ, H_SZ, jh0, tid);
  else
    d8_stage(WF, P.dwr + (long)dir * G4 * 1024, 1024, 1024,
                 P.dwh + (long)ld * G4 * H_SZ, H_SZ, H_SZ, jh0, tid);
  __syncthreads();
  float b4[4], c_reg[4];
  #pragma unroll
  for (int g = 0; g < 4; ++g) b4[g] = P.bcomb[(long)slot * G4 + g * 512 + jh];
  #pragma unroll
  for (int r = 0; r < 4; ++r)
    c_reg[r] = P.cst[(long)ld * HSLICE + (long)(mt0 * 16 + quad * 4 + r) * H_SZ + jh];

  for (int s = 0; s <= T_LEN; ++s) {
    const int p = s & 1;
    float4v acc[2] = {};
    if (layer == 0 && s < T_LEN)
      d8_mm_norm<4>(acc, WF, P.xF + (long)s * XFT, mt0, 0, lane);    // overlap zone
    gbar_wait(bar, bid, s);
    if (layer == 0) {
      if (s < T_LEN) {
        d8_mm_coh<16>(acc, WF, P.hst + (long)p * HPAR + (long)dir * HSLICE, mt0, 4, lane);
        d8_cell(acc, mt0, jh0, c_reg, b4,
                P.hst + (long)(1 - p) * HPAR + (long)dir * HSLICE, lane);
      }
    } else {
      if (s == 0) {
        if (tid < 64) {
          const long off = (long)(2 + dir) * HSLICE + ((long)rsw * 64 + tid) * 8;
          const unsigned long long* src = (const unsigned long long*)(P.hst + off);
          st_u64c((unsigned long long*)(P.hst + HPAR + off),     src[0]);
          st_u64c((unsigned long long*)(P.hst + HPAR + off) + 1, src[1]);
        }
      } else {
        d8_mm_coh<16>(acc, WF, P.hst + (long)p * HPAR + 0 * HSLICE, mt0, 0, lane);
        d8_mm_coh<16>(acc, WF, P.hst + (long)p * HPAR + 1 * HSLICE, mt0, 16, lane);
        d8_mm_coh<16>(acc, WF, P.hst + (long)p * HPAR + (long)(2 + dir) * HSLICE, mt0, 32, lane);
        d8_cell(acc, mt0, jh0, c_reg, b4,
                P.hst + (long)(1 - p) * HPAR + (long)(2 + dir) * HSLICE, lane);
      }
    }
    gbar_arrive(bar, bid, s + 1);
  }
}

// ============== dec NT=2 variant (private helpers, 256 blocks, dyn LDS) =====
// 16 blocks per leaf (256 blocks total).
__device__ __forceinline__ void g2_arrive(unsigned int* bar, int bid, unsigned g) {
  __syncthreads();
  if (threadIdx.x == 0) {
    unsigned old = __hip_atomic_fetch_add(bar + (bid & 15) * 16, 1u, __ATOMIC_RELAXED, SCOPE);
    if (old + 1 == 16u * g) {
      unsigned ro = __hip_atomic_fetch_add(bar + 256, 1u, __ATOMIC_RELAXED, SCOPE);
      if (ro + 1 == 16u * g) {
        #pragma unroll
        for (int i = 0; i < 8; ++i)
          __hip_atomic_store(bar + 320 + i * 16, g, __ATOMIC_RELAXED, SCOPE);
      }
    }
  }
}
__device__ __forceinline__ void g2_wait(unsigned int* bar, int bid, unsigned g) {
  if (g && threadIdx.x == 0) {
    while (__hip_atomic_load(bar + 320 + (bid & 7) * 16, __ATOMIC_RELAXED, SCOPE) < g)
      __builtin_amdgcn_s_sleep(2);
  }
  __syncthreads();
  asm volatile("" ::: "memory");
}

__device__ __forceinline__ void d2_stage(_Float16* WF,
    const _Float16* W1, long st1, int K1,
    const _Float16* W2, long st2, int K2, int jh0, int tid) {
  const int n8 = ((K1 + K2) >> 5) * 64;
  for (int idx = tid; idx < n8; idx += 512) {
    const int q = idx >> 6, l = idx & 63;
    const int c = l & 15, qd = l >> 4;
    const int j = (c >> 2) * 512 + jh0 + (c & 3);
    const int k = q * 32 + qd * 8;
    const _Float16* src = (k < K1) ? (W1 + (long)j * st1 + k)
                                   : (W2 + (long)j * st2 + (k - K1));
    *(half8*)(WF + (long)idx * 8) = *(const half8*)src;
  }
}
// A shared across two n-tiles: one A load feeds two MFMAs.
template <int NQ>
__device__ __forceinline__ void d2_mm_norm(float4v (&acc)[2][2], const _Float16* W0,
    const _Float16* W1, const _Float16* A, int mt0, int kq0, int lane) {
  const _Float16* wl0 = W0 + lane * 8;
  const _Float16* wl1 = W1 + lane * 8;
  const _Float16* ab = A + (long)mt0 * 512 + lane * 8;
  #pragma unroll
  for (int qq = 0; qq < NQ; ++qq) {
    const half8 af = *(const half8*)(ab + (long)qq * 4096);
    const int par = (kq0 + qq) & 1;
    acc[0][par] = __builtin_amdgcn_mfma_f32_16x16x32_f16(
        af, *(const half8*)(wl0 + (long)(kq0 + qq) * 512), acc[0][par], 0, 0, 0);
    acc[1][par] = __builtin_amdgcn_mfma_f32_16x16x32_f16(
        af, *(const half8*)(wl1 + (long)(kq0 + qq) * 512), acc[1][par], 0, 0, 0);
  }
}
template <int NQ>
__device__ __forceinline__ void d2_mm_coh(float4v (&acc)[2][2], const _Float16* W0,
    const _Float16* W1, const _Float16* A, int mt0, int kq0, int lane) {
  const _Float16* wl0 = W0 + lane * 8;
  const _Float16* wl1 = W1 + lane * 8;
  const _Float16* ab = A + (long)mt0 * 512 + lane * 8;
  #pragma unroll
  for (int qq = 0; qq < NQ; ++qq) {
    const half8 af = ld_h8c(ab + (long)qq * 4096);
    const int par = (kq0 + qq) & 1;
    acc[0][par] = __builtin_amdgcn_mfma_f32_16x16x32_f16(
        af, *(const half8*)(wl0 + (long)(kq0 + qq) * 512), acc[0][par], 0, 0, 0);
    acc[1][par] = __builtin_amdgcn_mfma_f32_16x16x32_f16(
        af, *(const half8*)(wl1 + (long)(kq0 + qq) * 512), acc[1][par], 0, 0, 0);
  }
}
// l1: 3 slices interleaved per k-chunk -> 3 independent coherent loads in flight.
__device__ __forceinline__ void d2_l1_mm(float4v (&acc)[2][2], const _Float16* W0,
    const _Float16* W1, const _Float16* A0, const _Float16* A1, const _Float16* A2,
    int mt0, int lane) {
  const _Float16* wl0 = W0 + lane * 8;
  const _Float16* wl1 = W1 + lane * 8;
  const long mo = (long)mt0 * 512 + lane * 8;
  const _Float16* ab0 = A0 + mo;
  const _Float16* ab1 = A1 + mo;
  const _Float16* ab2 = A2 + mo;
  #pragma unroll
  for (int qq = 0; qq < 16; ++qq) {
    const half8 af0 = ld_h8c(ab0 + (long)qq * 4096);
    const half8 af1 = ld_h8c(ab1 + (long)qq * 4096);
    const half8 af2 = ld_h8c(ab2 + (long)qq * 4096);
    const int par = qq & 1;
    acc[0][par] = __builtin_amdgcn_mfma_f32_16x16x32_f16(
        af0, *(const half8*)(wl0 + (long)qq * 512), acc[0][par], 0, 0, 0);
    acc[0][par] = __builtin_amdgcn_mfma_f32_16x16x32_f16(
        af1, *(const half8*)(wl0 + (long)(16 + qq) * 512), acc[0][par], 0, 0, 0);
    acc[0][par] = __builtin_amdgcn_mfma_f32_16x16x32_f16(
        af2, *(const half8*)(wl0 + (long)(32 + qq) * 512), acc[0][par], 0, 0, 0);
    acc[1][par] = __builtin_amdgcn_mfma_f32_16x16x32_f16(
        af0, *(const half8*)(wl1 + (long)qq * 512), acc[1][par], 0, 0, 0);
    acc[1][par] = __builtin_amdgcn_mfma_f32_16x16x32_f16(
        af1, *(const half8*)(wl1 + (long)(16 + qq) * 512), acc[1][par], 0, 0, 0);
    acc[1][par] = __builtin_amdgcn_mfma_f32_16x16x32_f16(
        af2, *(const half8*)(wl1 + (long)(32 + qq) * 512), acc[1][par], 0, 0, 0);
  }
}
__device__ __forceinline__ void d2_cell(float4v (&acc)[2][2], int mt0, int jhA, int jhB,
    float (&c_reg)[2][4], const float (&b4)[2][4], _Float16* hdst, int lane) {
  const int quad = lane >> 4;
  const bool wr = (lane & 12) == 0;
  const int sbase = (lane & 48) | (lane & 3);
  #pragma unroll
  for (int n = 0; n < 2; ++n) {
    const int jh0 = n ? jhB : jhA;
    #pragma unroll
    for (int r = 0; r < 4; ++r) {
      const float v = acc[n][0][r] + acc[n][1][r];
      const float iv = __shfl(v, sbase);
      const float fv = __shfl(v, sbase | 4);
      const float gv = __shfl(v, sbase | 8);
      const float ov = __shfl(v, sbase | 12);
      float h2 = 0.f;
      if (wr) {
        const float ig = iv + b4[n][0], fg = fv + b4[n][1];
        const float gg = gv + b4[n][2], og = ov + b4[n][3];
        const float si = 1.f / (1.f + __expf(-ig));
        const float sf = 1.f / (1.f + __expf(-fg));
        const float so = 1.f / (1.f + __expf(-og));
        const float eg = __expf(2.f * gg);
        const float tg = (eg - 1.f) / (eg + 1.f);
        const float c2 = sf * c_reg[n][r] + si * tg;
        c_reg[n][r] = c2;
        const float ec = __expf(2.f * c2);
        h2 = so * (ec - 1.f) / (ec + 1.f);
      }
      union { _Float16 f; unsigned short s; } hb; hb.f = (_Float16)h2;
      int b0 = (int)hb.s;
      int b1 = __shfl_xor(b0, 1);
      int lo = (b0 & 0xffff) | (b1 << 16);
      int hi = __shfl_xor(lo, 2);
      if ((lane & 15) == 0) {
        const unsigned long long u =
            (unsigned long long)(unsigned)lo | ((unsigned long long)(unsigned)hi << 32);
        const int m = mt0 * 16 + quad * 4 + r;
        st_u64c((unsigned long long*)(hdst + fragAddr(m, jh0)), u);
      }
    }
  }
}

__launch_bounds__(512, 2)
__global__ void dec_persist_nt2(PP P, unsigned int* bar) {
  extern __shared__ _Float16 WFD[];
  const int bid = blockIdx.x, tid = threadIdx.x;
  const int wave = tid >> 6, lane = tid & 63, quad = lane >> 4, jl = lane & 3;
  const int q = bid >> 6;              // 256 blocks: 0=l0f 1=l0b 2=l1f 3=l1b
  const int layer = q >> 1, dir = q & 1;
  const int cg = bid & 63;
  const int sw = (cg & 7) * 8 + (cg >> 3);  // bijective 0..63 spread
  const int jhA = sw * 4, jhB = (sw + 64) * 4;
  const int mt0 = wave;                // 8 waves, one 16-row m-tile each
  const int slot = 4 + layer * 2 + dir;
  const int ld = layer * 2 + dir;
  const int kqt = (layer == 0) ? 20 : 48;
  _Float16* W0 = WFD;
  _Float16* W1 = WFD + (long)kqt * 512;

  if (layer == 0) {
    d2_stage(W0, P.dw0 + (long)dir * G4 * C_IN, C_IN, C_IN,
                 P.dwh + (long)dir * G4 * H_SZ, H_SZ, H_SZ, jhA, tid);
    d2_stage(W1, P.dw0 + (long)dir * G4 * C_IN, C_IN, C_IN,
                 P.dwh + (long)dir * G4 * H_SZ, H_SZ, H_SZ, jhB, tid);
  } else {
    d2_stage(W0, P.dwr + (long)dir * G4 * 1024, 1024, 1024,
                 P.dwh + (long)ld * G4 * H_SZ, H_SZ, H_SZ, jhA, tid);
    d2_stage(W1, P.dwr + (long)dir * G4 * 1024, 1024, 1024,
                 P.dwh + (long)ld * G4 * H_SZ, H_SZ, H_SZ, jhB, tid);
  }
  __syncthreads();
  float b4[2][4], c_reg[2][4];
  #pragma unroll
  for (int n = 0; n < 2; ++n) {
    const int jh = (n ? jhB : jhA) + jl;
    #pragma unroll
    for (int g = 0; g < 4; ++g) b4[n][g] = P.bcomb[(long)slot * G4 + g * 512 + jh];
    #pragma unroll
    for (int r = 0; r < 4; ++r)
      c_reg[n][r] = P.cst[(long)ld * HSLICE + (long)(mt0 * 16 + quad * 4 + r) * H_SZ + jh];
  }

  for (int s = 0; s <= T_LEN; ++s) {
    const int p = s & 1;
    float4v acc[2][2] = {};
    if (layer == 0 && s < T_LEN)
      d2_mm_norm<4>(acc, W0, W1, P.xF + (long)s * XFT, mt0, 0, lane); // overlap zone
    g2_wait(bar, bid, s);
    if (layer == 0) {
      if (s < T_LEN) {
        d2_mm_coh<16>(acc, W0, W1, P.hst + (long)p * HPAR + (long)dir * HSLICE, mt0, 4, lane);
        d2_cell(acc, mt0, jhA, jhB, c_reg, b4,
                P.hst + (long)(1 - p) * HPAR + (long)dir * HSLICE, lane);
      }
    } else {
      if (s == 0) {
        // seed own h into parity 1 (step s=1 reads parity 1); src from enc1 final.
        const int idx = cg * 512 + tid;
        if (idx < 16384) {
          const long soff = (long)(2 + dir) * HSLICE;
          const unsigned long long* src = (const unsigned long long*)(P.hst + soff);
          st_u64c((unsigned long long*)(P.hst + HPAR + soff) + idx, src[idx]);
        }
      } else {
        const _Float16* base = P.hst + (long)p * HPAR;
        d2_l1_mm(acc, W0, W1, base, base + HSLICE, base + (long)(2 + dir) * HSLICE,
                 mt0, lane);
        d2_cell(acc, mt0, jhA, jhB, c_reg, b4,
                P.hst + (long)(1 - p) * HPAR + (long)(2 + dir) * HSLICE, lane);
      }
    }
    g2_arrive(bar, bid, s + 1);
  }
}

// ============== enc NT=2 variants (private helpers, 128 blocks) =============
// 16 leaves x 8 blocks.
__device__ __forceinline__ void e_arrive(unsigned int* bar, int bid, unsigned g) {
  __syncthreads();
  if (threadIdx.x == 0) {
    unsigned old = __hip_atomic_fetch_add(bar + (bid & 15) * 16, 1u, __ATOMIC_RELAXED, SCOPE);
    if (old + 1 == 8u * g) {
      unsigned ro = __hip_atomic_fetch_add(bar + 256, 1u, __ATOMIC_RELAXED, SCOPE);
      if (ro + 1 == 16u * g) {
        #pragma unroll
        for (int i = 0; i < 8; ++i)
          __hip_atomic_store(bar + 320 + i * 16, g, __ATOMIC_RELAXED, SCOPE);
      }
    }
  }
}
__device__ __forceinline__ void e_wait(unsigned int* bar, int bid, unsigned g) {
  if (g && threadIdx.x == 0) {
    while (__hip_atomic_load(bar + 320 + (bid & 7) * 16, __ATOMIC_RELAXED, SCOPE) < g)
      __builtin_amdgcn_s_sleep(2);
  }
  __syncthreads();
  asm volatile("" ::: "memory");
}

__device__ __forceinline__ void e2_stage(_Float16* WF,
    const _Float16* W1, long st1, int K1,
    const _Float16* W2, long st2, int K2, int jh0, int tid) {
  const int n8 = ((K1 + K2) >> 5) * 64;
  for (int idx = tid; idx < n8; idx += 512) {
    const int q = idx >> 6, l = idx & 63;
    const int c = l & 15, qd = l >> 4;
    const int j = (c >> 2) * 512 + jh0 + (c & 3);
    const int k = q * 32 + qd * 8;
    const _Float16* src = (k < K1) ? (W1 + (long)j * st1 + k)
                                   : (W2 + (long)j * st2 + (k - K1));
    *(half8*)(WF + (long)idx * 8) = *(const half8*)src;
  }
}
template <int NQ>
__device__ __forceinline__ void e2_mm_norm(float4v (&acc)[2][2], const _Float16* W0,
    const _Float16* W1, const _Float16* A, int mt0, int kq0, int lane) {
  const _Float16* wl0 = W0 + lane * 8;
  const _Float16* wl1 = W1 + lane * 8;
  const _Float16* ab = A + (long)mt0 * 512 + lane * 8;
  #pragma unroll
  for (int qq = 0; qq < NQ; ++qq) {
    const half8 af = *(const half8*)(ab + (long)qq * 4096);
    const int par = (kq0 + qq) & 1;
    acc[0][par] = __builtin_amdgcn_mfma_f32_16x16x32_f16(
        af, *(const half8*)(wl0 + (long)(kq0 + qq) * 512), acc[0][par], 0, 0, 0);
    acc[1][par] = __builtin_amdgcn_mfma_f32_16x16x32_f16(
        af, *(const half8*)(wl1 + (long)(kq0 + qq) * 512), acc[1][par], 0, 0, 0);
  }
}
template <int NQ>
__device__ __forceinline__ void e2_mm_coh(float4v (&acc)[2][2], const _Float16* W0,
    const _Float16* W1, const _Float16* A, int mt0, int kq0, int lane) {
  const _Float16* wl0 = W0 + lane * 8;
  const _Float16* wl1 = W1 + lane * 8;
  const _Float16* ab = A + (long)mt0 * 512 + lane * 8;
  #pragma unroll
  for (int qq = 0; qq < NQ; ++qq) {
    const half8 af = ld_h8c(ab + (long)qq * 4096);
    const int par = (kq0 + qq) & 1;
    acc[0][par] = __builtin_amdgcn_mfma_f32_16x16x32_f16(
        af, *(const half8*)(wl0 + (long)(kq0 + qq) * 512), acc[0][par], 0, 0, 0);
    acc[1][par] = __builtin_amdgcn_mfma_f32_16x16x32_f16(
        af, *(const half8*)(wl1 + (long)(kq0 + qq) * 512), acc[1][par], 0, 0, 0);
  }
}
__device__ __forceinline__ void e2_cell(float4v (&acc)[2][2], int mt0, int jhA, int jhB,
    float (&c_reg)[2][4], const float (&b4)[2][4], _Float16* hdst,
    _Float16* ydst, int ycolA, int ycolB, int lane) {
  const int quad = lane >> 4;
  const bool wr = (lane & 12) == 0;
  const int sbase = (lane & 48) | (lane & 3);
  #pragma unroll
  for (int n = 0; n < 2; ++n) {
    const int jh0 = n ? jhB : jhA;
    const int ycol = n ? ycolB : ycolA;
    #pragma unroll
    for (int r = 0; r < 4; ++r) {
      const float v = acc[n][0][r] + acc[n][1][r];
      const float iv = __shfl(v, sbase);
      const float fv = __shfl(v, sbase | 4);
      const float gv = __shfl(v, sbase | 8);
      const float ov = __shfl(v, sbase | 12);
      float h2 = 0.f;
      if (wr) {
        const float ig = iv + b4[n][0], fg = fv + b4[n][1];
        const float gg = gv + b4[n][2], og = ov + b4[n][3];
        const float si = 1.f / (1.f + __expf(-ig));
        const float sf = 1.f / (1.f + __expf(-fg));
        const float so = 1.f / (1.f + __expf(-og));
        const float eg = __expf(2.f * gg);
        const float tg = (eg - 1.f) / (eg + 1.f);
        const float c2 = sf * c_reg[n][r] + si * tg;
        c_reg[n][r] = c2;
        const float ec = __expf(2.f * c2);
        h2 = so * (ec - 1.f) / (ec + 1.f);
      }
      union { _Float16 f; unsigned short s; } hb; hb.f = (_Float16)h2;
      int b0 = (int)hb.s;
      int b1 = __shfl_xor(b0, 1);
      int lo = (b0 & 0xffff) | (b1 << 16);
      int hi = __shfl_xor(lo, 2);
      if ((lane & 15) == 0) {
        const unsigned long long u =
            (unsigned long long)(unsigned)lo | ((unsigned long long)(unsigned)hi << 32);
        const int m = mt0 * 16 + quad * 4 + r;
        st_u64c((unsigned long long*)(hdst + fragAddr(m, jh0)), u);
        if (ydst) *(unsigned long long*)(ydst + fragAddr(m, ycol)) = u;
      }
    }
  }
}

__launch_bounds__(512, 2)
__global__ void enc0_nt2(PP P, unsigned int* bar) {
  const int bid = blockIdx.x, tid = threadIdx.x;
  const int wave = tid >> 6, lane = tid & 63, quad = lane >> 4, jl = lane & 3;
  __shared__ _Float16 WF[20480];       // kqt=20 x 2 ntiles = 40 KB
  const int dir = bid >> 6, cg = bid & 63;
  const int sw = (cg & 7) * 8 + (cg >> 3);
  const int jhA = sw * 4, jhB = (sw + 64) * 4;
  const int mt0 = wave;
  _Float16* W0 = WF;
  _Float16* W1 = WF + 10240;

  e2_stage(W0, P.ew0 + (long)dir * G4 * C_IN, C_IN, C_IN,
               P.ewh + (long)dir * G4 * H_SZ, H_SZ, H_SZ, jhA, tid);
  e2_stage(W1, P.ew0 + (long)dir * G4 * C_IN, C_IN, C_IN,
               P.ewh + (long)dir * G4 * H_SZ, H_SZ, H_SZ, jhB, tid);
  __syncthreads();
  float b4[2][4], c_reg[2][4];
  #pragma unroll
  for (int n = 0; n < 2; ++n) {
    const int jh = (n ? jhB : jhA) + jl;
    #pragma unroll
    for (int g = 0; g < 4; ++g) b4[n][g] = P.bcomb[(long)dir * G4 + g * 512 + jh];
    #pragma unroll
    for (int r = 0; r < 4; ++r)
      c_reg[n][r] = P.cst[(long)dir * HSLICE + (long)(mt0 * 16 + quad * 4 + r) * H_SZ + jh];
  }

  for (int s = 0; s < T_LEN; ++s) {
    const int p = s & 1;
    const int td = dir ? (T_LEN - 1 - s) : s;
    float4v acc[2][2] = {};
    e2_mm_norm<4>(acc, W0, W1, P.xF + (long)td * XFT, mt0, 0, lane); // overlap zone
    e_wait(bar, bid, s);
    e2_mm_coh<16>(acc, W0, W1, P.hst + (long)p * HPAR + (long)dir * HSLICE, mt0, 4, lane);
    e2_cell(acc, mt0, jhA, jhB, c_reg, b4,
            P.hst + (long)(1 - p) * HPAR + (long)dir * HSLICE,
            P.y0F + (long)td * Y0T, dir * 512 + jhA, dir * 512 + jhB, lane);
    e_arrive(bar, bid, s + 1);
  }
  if ((lane & 12) == 0) {
    #pragma unroll
    for (int n = 0; n < 2; ++n) {
      const int jh = (n ? jhB : jhA) + jl;
      #pragma unroll
      for (int r = 0; r < 4; ++r)
        P.cst[(long)dir * HSLICE + (long)(mt0 * 16 + quad * 4 + r) * H_SZ + jh] =
            c_reg[n][r];
    }
  }
}

__launch_bounds__(512, 2)
__global__ void enc1_nt2(PP P, unsigned int* bar) {
  extern __shared__ _Float16 WFE[];    // kqt=48 x 2 ntiles = 96 KB (dynamic)
  const int bid = blockIdx.x, tid = threadIdx.x;
  const int wave = tid >> 6, lane = tid & 63, quad = lane >> 4, jl = lane & 3;
  const int dir = bid >> 6, cg = bid & 63;
  const int sw = (cg & 7) * 8 + (cg >> 3);
  const int jhA = sw * 4, jhB = (sw + 64) * 4;
  const int mt0 = wave;
  const int ld = 2 + dir;
  _Float16* W0 = WFE;
  _Float16* W1 = WFE + 24576;

  e2_stage(W0, P.ewr + (long)dir * G4 * 1024, 1024, 1024,
               P.ewh + (long)ld * G4 * H_SZ, H_SZ, H_SZ, jhA, tid);
  e2_stage(W1, P.ewr + (long)dir * G4 * 1024, 1024, 1024,
               P.ewh + (long)ld * G4 * H_SZ, H_SZ, H_SZ, jhB, tid);
  __syncthreads();
  float b4[2][4], c_reg[2][4];
  #pragma unroll
  for (int n = 0; n < 2; ++n) {
    const int jh = (n ? jhB : jhA) + jl;
    #pragma unroll
    for (int g = 0; g < 4; ++g) b4[n][g] = P.bcomb[(long)ld * G4 + g * 512 + jh];
    #pragma unroll
    for (int r = 0; r < 4; ++r)
      c_reg[n][r] = P.cst[(long)ld * HSLICE + (long)(mt0 * 16 + quad * 4 + r) * H_SZ + jh];
  }

  for (int s = 0; s < T_LEN; ++s) {
    const int p = s & 1;
    const int td = dir ? (T_LEN - 1 - s) : s;
    float4v acc[2][2] = {};
    e2_mm_norm<32>(acc, W0, W1, P.y0F + (long)td * Y0T, mt0, 0, lane); // overlap zone
    e_wait(bar, bid, s);
    e2_mm_coh<16>(acc, W0, W1, P.hst + (long)p * HPAR + (long)ld * HSLICE, mt0, 32, lane);
    e2_cell(acc, mt0, jhA, jhB, c_reg, b4,
            P.hst + (long)(1 - p) * HPAR + (long)ld * HSLICE, nullptr, 0, 0, lane);
    e_arrive(bar, bid, s + 1);
  }
  if ((lane & 12) == 0) {
    #pragma unroll
    for (int n = 0; n < 2; ++n) {
      const int jh = (n ? jhB : jhA) + jl;
      #pragma unroll
      for (int r = 0; r < 4; ++r)
        P.cst[(long)ld * HSLICE + (long)(mt0 * 16 + quad * 4 + r) * H_SZ + jh] =
            c_reg[n][r];
    }
  }
}

// ---------------------------------------------------------------------------
__global__ void f2h(const float* __restrict__ src, _Float16* __restrict__ dst, long n) {
  for (long i = blockIdx.x * 256L + threadIdx.x; i < n; i += (long)gridDim.x * 256)
    dst[i] = (_Float16)src[i];
}

__global__ void x_to_frag(const float* __restrict__ x, _Float16* __restrict__ xF) {
  const int t = blockIdx.x, b = blockIdx.y, c = threadIdx.x;
  xF[(long)t * XFT + fragAddr(b, c)] = (_Float16)x[((long)b * T_LEN + t) * C_IN + c];
}

__global__ void h0_to_frag(const float* __restrict__ h0, _Float16* __restrict__ hstF) {
  const long i = blockIdx.x * 256L + threadIdx.x;
  const int ld = (int)(i >> 16);
  const int b = (int)((i >> 9) & 127);
  const int k = (int)(i & 511);
  hstF[(long)ld * HSLICE + fragAddr(b, k)] = (_Float16)h0[i];
}

__global__ void bias_combine(const float* __restrict__ e_bih, const float* __restrict__ e_bhh,
                             const float* __restrict__ d_bih, const float* __restrict__ d_bhh,
                             float* __restrict__ bcomb) {
  const int i = blockIdx.x * 256 + threadIdx.x;
  const int slot = i >> 11;
  const int j = i & 2047;
  float v;
  if (slot < 4) v = e_bih[slot * 2048 + j] + e_bhh[slot * 2048 + j];
  else          v = d_bih[(slot - 4) * 2048 + j] + d_bhh[(slot - 4) * 2048 + j];
  bcomb[i] = v;
}

__global__ void final_linear(const _Float16* __restrict__ hF,  // hst + HPAR
                             const float* __restrict__ lin_w, const float* __restrict__ lb,
                             float* __restrict__ out) {
  const int tid = threadIdx.x;
  const int o = tid & 127;
  const int b = blockIdx.x * 2 + (tid >> 7);
  const float* w = lin_w + (long)o * 1024;
  float acc = 0.f;
  for (int k = 0; k < H_SZ; ++k) acc += (float)hF[2L * HSLICE + fragAddr(b, k)] * w[k];
  for (int k = 0; k < H_SZ; ++k) acc += (float)hF[3L * HSLICE + fragAddr(b, k)] * w[H_SZ + k];
  out[(long)b * 128 + o] = acc + lb[o];
}

__global__ void fill_val(float* __restrict__ p, int n, float v) {
  const int i = blockIdx.x * 256 + threadIdx.x;
  if (i < n) p[i] = v;
}

// ---------------------------------------------------------------------------
extern "C" void kernel_launch(void* const* d_in, const int* in_sizes, int n_in,
                              void* d_out, int out_size, void* d_ws, size_t ws_size,
                              hipStream_t stream) {
  (void)in_sizes; (void)n_in;
  const float* x      = (const float*)d_in[0];
  const float* h0     = (const float*)d_in[1];
  const float* c0     = (const float*)d_in[2];
  const float* e_wih0 = (const float*)d_in[3];
  const float* e_wihr = (const float*)d_in[4];
  const float* e_whh  = (const float*)d_in[5];
  const float* e_bih  = (const float*)d_in[6];
  const float* e_bhh  = (const float*)d_in[7];
  const float* dw_ih0 = (const float*)d_in[8];
  const float* dw_ihr = (const float*)d_in[9];
  const float* dw_hh  = (const float*)d_in[10];
  const float* db_ih  = (const float*)d_in[11];
  const float* db_hh  = (const float*)d_in[12];
  const float* lin_w  = (const float*)d_in[13];
  const float* lin_b  = (const float*)d_in[14];
  float* out = (float*)d_out;

  char* wsb = (char*)d_ws;
  size_t off = 0;
  auto carve = [&](size_t bytes) -> void* {
    void* pp = wsb + off;
    off += (bytes + 255) & ~(size_t)255;
    return pp;
  };
  _Float16* xF  = (_Float16*)carve((size_t)T_LEN * XFT * 2);
  _Float16* ew0 = (_Float16*)carve(2L * G4 * C_IN * 2);
  _Float16* ewr = (_Float16*)carve(2L * G4 * 1024 * 2);
  _Float16* ewh = (_Float16*)carve(4L * G4 * H_SZ * 2);
  _Float16* dw0 = (_Float16*)carve(2L * G4 * C_IN * 2);
  _Float16* dwr = (_Float16*)carve(2L * G4 * 1024 * 2);
  _Float16* dwh = (_Float16*)carve(4L * G4 * H_SZ * 2);
  _Float16* y0F = (_Float16*)carve((size_t)T_LEN * Y0T * 2);
  float* bcomb  = (float*)carve(8L * G4 * 4);
  _Float16* hst = (_Float16*)carve(2L * HPAR * 2);
  float* cst    = (float*)carve(4L * HSLICE * 4);
  unsigned int* bar0 = (unsigned int*)carve(2048);
  unsigned int* bar1 = (unsigned int*)carve(2048);
  unsigned int* bar2 = (unsigned int*)carve(2048);

  if (off > ws_size) {
    hipMemsetAsync(d_out, 0, (size_t)out_size * 4, stream);
    return;
  }

  // ---- prep ----
  hipMemsetAsync(bar0, 0, 3 * 2048, stream);
  x_to_frag<<<dim3(T_LEN, B_SZ), C_IN, 0, stream>>>(x, xF);
  f2h<<<64,  256, 0, stream>>>(e_wih0, ew0, 2L * G4 * C_IN);
  f2h<<<256, 256, 0, stream>>>(e_wihr, ewr, 2L * G4 * 1024);
  f2h<<<256, 256, 0, stream>>>(e_whh,  ewh, 4L * G4 * H_SZ);
  f2h<<<64,  256, 0, stream>>>(dw_ih0, dw0, 2L * G4 * C_IN);
  f2h<<<256, 256, 0, stream>>>(dw_ihr, dwr, 2L * G4 * 1024);
  f2h<<<256, 256, 0, stream>>>(dw_hh,  dwh, 4L * G4 * H_SZ);
  h0_to_frag<<<1024, 256, 0, stream>>>(h0, hst);
  bias_combine<<<64, 256, 0, stream>>>(e_bih, e_bhh, db_ih, db_hh, bcomb);
  hipMemcpyAsync(cst, c0, 4L * HSLICE * 4, hipMemcpyDeviceToDevice, stream);

  // ---- variant gates ----
  int use_e0 = 0;
  {
    int mab = 0;
    if (hipOccupancyMaxActiveBlocksPerMultiprocessor(&mab, enc0_nt2, 512, 0) == hipSuccess
        && mab >= 1)
      use_e0 = 1;
  }
  int use_e1 = 0;
  if (hipFuncSetAttribute(reinterpret_cast<const void*>(enc1_nt2),
                          hipFuncAttributeMaxDynamicSharedMemorySize, 98304) == hipSuccess) {
    int mab = 0;
    if (hipOccupancyMaxActiveBlocksPerMultiprocessor(&mab, enc1_nt2, 512, 98304)
            == hipSuccess && mab >= 1)
      use_e1 = 1;
  }
  int use_nt2 = 0;
  if (hipFuncSetAttribute(reinterpret_cast<const void*>(dec_persist_nt2),
                          hipFuncAttributeMaxDynamicSharedMemorySize, 98304) == hipSuccess) {
    int mab = 0;
    if (hipOccupancyMaxActiveBlocksPerMultiprocessor(&mab, dec_persist_nt2, 512, 98304)
            == hipSuccess && mab >= 1)
      use_nt2 = 1;
  }
  int mab8 = 0;
  if (hipOccupancyMaxActiveBlocksPerMultiprocessor(&mab8, dec_persist8, 512, 0) != hipSuccess)
    mab8 = 0;

  // ---- three persistent cooperative kernels (split-phase barriers) ----
  PP P{ xF, ew0, ewr, ewh, dw0, dwr, dwh, bcomb, y0F, hst, cst };
  hipError_t e;
  {
    void* a0[] = { &P, &bar0 };
    if (use_e0) {
      e = hipLaunchCooperativeKernel((void*)enc0_nt2, dim3(128), dim3(512), a0, 0, stream);
      if (e != hipSuccess)
        e = hipLaunchCooperativeKernel((void*)enc0_persist, dim3(512), dim3(256), a0, 0, stream);
    } else {
      e = hipLaunchCooperativeKernel((void*)enc0_persist, dim3(512), dim3(256), a0, 0, stream);
    }
    if (e != hipSuccess) { fill_val<<<64, 256, 0, stream>>>(out, 16384, 1.0e4f); return; }
  }
  {
    void* a1[] = { &P, &bar1 };
    if (use_e1) {
      e = hipLaunchCooperativeKernel((void*)enc1_nt2, dim3(128), dim3(512), a1, 98304, stream);
      if (e != hipSuccess)
        e = hipLaunchCooperativeKernel((void*)enc1_persist, dim3(512), dim3(256), a1, 0, stream);
    } else {
      e = hipLaunchCooperativeKernel((void*)enc1_persist, dim3(512), dim3(256), a1, 0, stream);
    }
    if (e != hipSuccess) { fill_val<<<64, 256, 0, stream>>>(out, 16384, 2.0e4f); return; }
  }
  {
    void* a2[] = { &P, &bar2 };
    if (use_nt2) {
      e = hipLaunchCooperativeKernel((void*)dec_persist_nt2, dim3(256), dim3(512), a2,
                                     98304, stream);
      if (e != hipSuccess) {
        if (mab8 >= 2)
          e = hipLaunchCooperativeKernel((void*)dec_persist8, dim3(512), dim3(512), a2, 0, stream);
        else
          e = hipLaunchCooperativeKernel((void*)dec_persist, dim3(512), dim3(256), a2, 0, stream);
      }
    } else if (mab8 >= 2) {
      e = hipLaunchCooperativeKernel((void*)dec_persist8, dim3(512), dim3(512), a2, 0, stream);
    } else {
      e = hipLaunchCooperativeKernel((void*)dec_persist, dim3(512), dim3(256), a2, 0, stream);
    }
    if (e != hipSuccess) { fill_val<<<64, 256, 0, stream>>>(out, 16384, 4.0e4f); return; }
  }

  // ---- final linear on decoder l1 t=511 output (parity 1, ld 2/3) ----
  final_linear<<<64, 256, 0, stream>>>(hst + HPAR, lin_w, lin_b, out);
}

// Round 9
// 12913.225 us; speedup vs baseline: 1.2614x; 1.2614x over previous
//
#include <hip/hip_runtime.h>
#include <hip/hip_cooperative_groups.h>

#define T_LEN 512
#define B_SZ  128
#define C_IN  128
#define H_SZ  512
#define G4    2048
#define HSLICE 65536   // halves per hF (ld) slice
#define HPAR  262144   // halves per parity (4 slices)
#define XFT   16384    // halves per xF[t]
#define Y0T   131072   // halves per y0F[t]

typedef _Float16 half8 __attribute__((ext_vector_type(8)));
typedef float    float4v __attribute__((ext_vector_type(4)));

#define SCOPE __HIP_MEMORY_SCOPE_AGENT

// Coherent (L2-bypass, L3-backed) helpers — relaxed: no cache flushes.
__device__ __forceinline__ half8 ld_h8c(const _Float16* p) {
  const unsigned long long* q = (const unsigned long long*)p;
  union { unsigned long long u[2]; half8 h; } v;
  v.u[0] = __hip_atomic_load(q,     __ATOMIC_RELAXED, SCOPE);
  v.u[1] = __hip_atomic_load(q + 1, __ATOMIC_RELAXED, SCOPE);
  return v.h;
}
__device__ __forceinline__ void st_u64c(unsigned long long* p, unsigned long long x) {
  __hip_atomic_store(p, x, __ATOMIC_RELAXED, SCOPE);
}

struct PP {
  const _Float16* xF;
  const _Float16 *ew0, *ewr, *ewh, *dw0, *dwr, *dwh;
  const float* bcomb;
  _Float16* y0F;
  _Float16* hst;
  float*    cst;
};

// ---- split-phase grid barrier: 16 leaves x 32 blocks, 8 per-XCD gen mirrors.
// (baseline relaxed protocol — empirically passing; kept byte-identical)
__device__ __forceinline__ void gbar_arrive(unsigned int* bar, int bid, unsigned g) {
  __syncthreads();                       // drains vmcnt: release
  if (threadIdx.x == 0) {
    unsigned old = __hip_atomic_fetch_add(bar + (bid & 15) * 16, 1u, __ATOMIC_RELAXED, SCOPE);
    if (old + 1 == 32u * g) {
      unsigned ro = __hip_atomic_fetch_add(bar + 256, 1u, __ATOMIC_RELAXED, SCOPE);
      if (ro + 1 == 16u * g) {
        #pragma unroll
        for (int i = 0; i < 8; ++i)
          __hip_atomic_store(bar + 320 + i * 16, g, __ATOMIC_RELAXED, SCOPE);
      }
    }
  }
}
__device__ __forceinline__ void gbar_wait(unsigned int* bar, int bid, unsigned g) {
  if (g && threadIdx.x == 0) {
    while (__hip_atomic_load(bar + 320 + (bid & 7) * 16, __ATOMIC_RELAXED, SCOPE) < g)
      __builtin_amdgcn_s_sleep(2);
  }
  __syncthreads();
  asm volatile("" ::: "memory");
}

// frag layout: element (m,k) at (k>>5)*4096 + (m>>4)*512 + ((k>>3)&3)*128 + (m&15)*8 + (k&7)
__device__ __forceinline__ long fragAddr(int m, int k) {
  return (long)(k >> 5) * 4096 + (m >> 4) * 512 + ((k >> 3) & 3) * 128 + (m & 15) * 8 + (k & 7);
}

// Stage 16 gate-cols of [W1;W2] (k-concat) into LDS (normal cached loads).
__device__ __forceinline__ void stage_w2(_Float16* WF,
    const _Float16* W1, long st1, int K1,
    const _Float16* W2, long st2, int K2, int jh0, int tid) {
  const int n8 = ((K1 + K2) >> 5) * 64;
  for (int idx = tid; idx < n8; idx += 256) {
    const int q = idx >> 6, l = idx & 63;
    const int c = l & 15, qd = l >> 4;
    const int j = (c >> 2) * 512 + jh0 + (c & 3);
    const int k = q * 32 + qd * 8;
    const _Float16* src = (k < K1) ? (W1 + (long)j * st1 + k)
                                   : (W2 + (long)j * st2 + (k - K1));
    *(half8*)(WF + (long)idx * 8) = *(const half8*)src;
  }
}

// MFMA over NQ k-chunks, A via normal cached loads.
template <int NQ, int MTS>
__device__ __forceinline__ void mm_norm(float4v (&acc)[MTS][2], const _Float16* WF,
                                        const _Float16* A, int mt0, int kq0, int lane) {
  const _Float16* wl = WF + lane * 8;
  const _Float16* ab = A + (long)mt0 * 512 + lane * 8;
  #pragma unroll
  for (int qq = 0; qq < NQ; ++qq) {
    const half8 bf = *(const half8*)(wl + (long)(kq0 + qq) * 512);
    #pragma unroll
    for (int mt = 0; mt < MTS; ++mt) {
      const half8 af = *(const half8*)(ab + (long)mt * 512 + (long)qq * 4096);
      acc[mt][(kq0 + qq) & 1] =
          __builtin_amdgcn_mfma_f32_16x16x32_f16(af, bf, acc[mt][(kq0 + qq) & 1], 0, 0, 0);
    }
  }
}
// MFMA over NQ k-chunks, A via coherent L3 loads (recurrent h).
template <int NQ, int MTS>
__device__ __forceinline__ void mm_coh(float4v (&acc)[MTS][2], const _Float16* WF,
                                       const _Float16* A, int mt0, int kq0, int lane) {
  const _Float16* wl = WF + lane * 8;
  const _Float16* ab = A + (long)mt0 * 512 + lane * 8;
  #pragma unroll
  for (int qq = 0; qq < NQ; ++qq) {
    const half8 bf = *(const half8*)(wl + (long)(kq0 + qq) * 512);
    #pragma unroll
    for (int mt = 0; mt < MTS; ++mt) {
      const half8 af = ld_h8c(ab + (long)mt * 512 + (long)qq * 4096);
      acc[mt][(kq0 + qq) & 1] =
          __builtin_amdgcn_mfma_f32_16x16x32_f16(af, bf, acc[mt][(kq0 + qq) & 1], 0, 0, 0);
    }
  }
}

// Cell update + packed u64 h-store (atomic) and optional y-store (normal).
template <int MTS>
__device__ __forceinline__ void cell_store(float4v (&acc)[MTS][2], int mt0, int jh0,
    float* c_reg, const float* b4, _Float16* hdst, _Float16* ydst, int ycol0, int lane) {
  const int quad = lane >> 4, jl = lane & 3;
  const bool wr = (lane & 12) == 0;
  const int sbase = (lane & 48) | jl;
  #pragma unroll
  for (int mt = 0; mt < MTS; ++mt) {
    #pragma unroll
    for (int r = 0; r < 4; ++r) {
      const float v = acc[mt][0][r] + acc[mt][1][r];
      const float iv = __shfl(v, sbase);
      const float fv = __shfl(v, sbase | 4);
      const float gv = __shfl(v, sbase | 8);
      const float ov = __shfl(v, sbase | 12);
      float h2 = 0.f;
      if (wr) {
        const float ig = iv + b4[0], fg = fv + b4[1], gg = gv + b4[2], og = ov + b4[3];
        const float si = 1.f / (1.f + __expf(-ig));
        const float sf = 1.f / (1.f + __expf(-fg));
        const float so = 1.f / (1.f + __expf(-og));
        const float eg = __expf(2.f * gg);
        const float tg = (eg - 1.f) / (eg + 1.f);
        const float c2 = sf * c_reg[mt * 4 + r] + si * tg;
        c_reg[mt * 4 + r] = c2;
        const float ec = __expf(2.f * c2);
        h2 = so * (ec - 1.f) / (ec + 1.f);
      }
      union { _Float16 f; unsigned short s; } hb; hb.f = (_Float16)h2;
      int b0 = (int)hb.s;
      int b1 = __shfl_xor(b0, 1);
      int lo = (b0 & 0xffff) | (b1 << 16);
      int hi = __shfl_xor(lo, 2);
      if ((lane & 15) == 0) {
        const unsigned long long u =
            (unsigned long long)(unsigned)lo | ((unsigned long long)(unsigned)hi << 32);
        const int m = (mt0 + mt) * 16 + quad * 4 + r;
        st_u64c((unsigned long long*)(hdst + fragAddr(m, jh0)), u);
        if (ydst) *(unsigned long long*)(ydst + fragAddr(m, ycol0)) = u;
      }
    }
  }
}

// ====================== persistent kernels (baseline fallbacks) =============
__launch_bounds__(256, 2)
__global__ void enc0_persist(PP P, unsigned int* bar) {
  const int bid = blockIdx.x, tid = threadIdx.x;
  const int wave = tid >> 6, lane = tid & 63, quad = lane >> 4;
  __shared__ _Float16 WF[24576];
  const int dir = bid >> 8, mg = (bid >> 7) & 1, rsw = bid & 127;
  const int nidx = (rsw & 7) * 16 + (rsw >> 3);
  const int jh0 = nidx * 4, jh = jh0 + (lane & 3);
  const int mt0 = mg * 4 + wave;

  stage_w2(WF, P.ew0 + (long)dir * G4 * C_IN, C_IN, C_IN,
               P.ewh + (long)dir * G4 * H_SZ, H_SZ, H_SZ, jh0, tid);
  __syncthreads();
  float b4[4], c_reg[4];
  #pragma unroll
  for (int g = 0; g < 4; ++g) b4[g] = P.bcomb[(long)dir * G4 + g * 512 + jh];
  #pragma unroll
  for (int r = 0; r < 4; ++r)
    c_reg[r] = P.cst[(long)dir * HSLICE + (long)(mt0 * 16 + quad * 4 + r) * H_SZ + jh];

  for (int s = 0; s < T_LEN; ++s) {
    const int p = s & 1;
    const int td = dir ? (T_LEN - 1 - s) : s;
    float4v acc[1][2] = {};
    mm_norm<4, 1>(acc, WF, P.xF + (long)td * XFT, mt0, 0, lane);     // overlap zone
    gbar_wait(bar, bid, s);
    mm_coh<16, 1>(acc, WF, P.hst + (long)p * HPAR + (long)dir * HSLICE, mt0, 4, lane);
    cell_store<1>(acc, mt0, jh0, c_reg, b4,
                  P.hst + (long)(1 - p) * HPAR + (long)dir * HSLICE,
                  P.y0F + (long)td * Y0T, dir * 512 + jh0, lane);
    gbar_arrive(bar, bid, s + 1);
  }
  if ((lane & 12) == 0) {
    #pragma unroll
    for (int r = 0; r < 4; ++r)
      P.cst[(long)dir * HSLICE + (long)(mt0 * 16 + quad * 4 + r) * H_SZ + jh] = c_reg[r];
  }
}

__launch_bounds__(256, 2)
__global__ void enc1_persist(PP P, unsigned int* bar) {
  const int bid = blockIdx.x, tid = threadIdx.x;
  const int wave = tid >> 6, lane = tid & 63, quad = lane >> 4;
  __shared__ _Float16 WF[24576];
  const int dir = bid >> 8, mg = (bid >> 7) & 1, rsw = bid & 127;
  const int nidx = (rsw & 7) * 16 + (rsw >> 3);
  const int jh0 = nidx * 4, jh = jh0 + (lane & 3);
  const int mt0 = mg * 4 + wave;
  const int ld = 2 + dir;

  stage_w2(WF, P.ewr + (long)dir * G4 * 1024, 1024, 1024,
               P.ewh + (long)ld * G4 * H_SZ, H_SZ, H_SZ, jh0, tid);
  __syncthreads();
  float b4[4], c_reg[4];
  #pragma unroll
  for (int g = 0; g < 4; ++g) b4[g] = P.bcomb[(long)ld * G4 + g * 512 + jh];
  #pragma unroll
  for (int r = 0; r < 4; ++r)
    c_reg[r] = P.cst[(long)ld * HSLICE + (long)(mt0 * 16 + quad * 4 + r) * H_SZ + jh];

  for (int s = 0; s < T_LEN; ++s) {
    const int p = s & 1;
    const int td = dir ? (T_LEN - 1 - s) : s;
    float4v acc[1][2] = {};
    mm_norm<32, 1>(acc, WF, P.y0F + (long)td * Y0T, mt0, 0, lane);   // overlap zone
    gbar_wait(bar, bid, s);
    mm_coh<16, 1>(acc, WF, P.hst + (long)p * HPAR + (long)ld * HSLICE, mt0, 32, lane);
    cell_store<1>(acc, mt0, jh0, c_reg, b4,
                  P.hst + (long)(1 - p) * HPAR + (long)ld * HSLICE, nullptr, 0, lane);
    gbar_arrive(bar, bid, s + 1);
  }
  if ((lane & 12) == 0) {
    #pragma unroll
    for (int r = 0; r < 4; ++r)
      P.cst[(long)ld * HSLICE + (long)(mt0 * 16 + quad * 4 + r) * H_SZ + jh] = c_reg[r];
  }
}

__launch_bounds__(256, 2)
__global__ void dec_persist(PP P, unsigned int* bar) {
  const int bid = blockIdx.x, tid = threadIdx.x;
  const int wave = tid >> 6, lane = tid & 63, quad = lane >> 4;
  __shared__ _Float16 WF[24576];
  const int q = bid >> 7;              // 0=l0f 1=l0b 2=l1f 3=l1b
  const int layer = q >> 1, dir = q & 1;
  const int rsw = bid & 127;
  const int nidx = (rsw & 7) * 16 + (rsw >> 3);
  const int jh0 = nidx * 4, jh = jh0 + (lane & 3);
  const int mt0 = wave * 2;            // MTS=2
  const int slot = 4 + layer * 2 + dir;
  const int ld = layer * 2 + dir;

  if (layer == 0)
    stage_w2(WF, P.dw0 + (long)dir * G4 * C_IN, C_IN, C_IN,
                 P.dwh + (long)dir * G4 * H_SZ, H_SZ, H_SZ, jh0, tid);
  else
    stage_w2(WF, P.dwr + (long)dir * G4 * 1024, 1024, 1024,
                 P.dwh + (long)ld * G4 * H_SZ, H_SZ, H_SZ, jh0, tid);
  __syncthreads();
  float b4[4], c_reg[8];
  #pragma unroll
  for (int g = 0; g < 4; ++g) b4[g] = P.bcomb[(long)slot * G4 + g * 512 + jh];
  #pragma unroll
  for (int mt = 0; mt < 2; ++mt)
    #pragma unroll
    for (int r = 0; r < 4; ++r)
      c_reg[mt * 4 + r] =
          P.cst[(long)ld * HSLICE + (long)((mt0 + mt) * 16 + quad * 4 + r) * H_SZ + jh];

  for (int s = 0; s <= T_LEN; ++s) {
    const int p = s & 1;
    float4v acc[2][2] = {};
    if (layer == 0 && s < T_LEN)
      mm_norm<4, 2>(acc, WF, P.xF + (long)s * XFT, mt0, 0, lane);    // overlap zone
    gbar_wait(bar, bid, s);
    if (layer == 0) {
      if (s < T_LEN) {
        mm_coh<16, 2>(acc, WF, P.hst + (long)p * HPAR + (long)dir * HSLICE, mt0, 4, lane);
        cell_store<2>(acc, mt0, jh0, c_reg, b4,
                      P.hst + (long)(1 - p) * HPAR + (long)dir * HSLICE, nullptr, 0, lane);
      }
    } else {
      if (s == 0) {
        // seed own h into parity 1 (step s=1 reads parity 1); src from prev kernel.
        if (tid < 64) {
          const long off = (long)(2 + dir) * HSLICE + ((long)rsw * 64 + tid) * 8;
          const unsigned long long* src = (const unsigned long long*)(P.hst + off);
          st_u64c((unsigned long long*)(P.hst + HPAR + off),     src[0]);
          st_u64c((unsigned long long*)(P.hst + HPAR + off) + 1, src[1]);
        }
      } else {
        mm_coh<16, 2>(acc, WF, P.hst + (long)p * HPAR + 0 * HSLICE, mt0, 0, lane);
        mm_coh<16, 2>(acc, WF, P.hst + (long)p * HPAR + 1 * HSLICE, mt0, 16, lane);
        mm_coh<16, 2>(acc, WF, P.hst + (long)p * HPAR + (long)(2 + dir) * HSLICE, mt0, 32, lane);
        cell_store<2>(acc, mt0, jh0, c_reg, b4,
                      P.hst + (long)(1 - p) * HPAR + (long)(2 + dir) * HSLICE, nullptr, 0, lane);
      }
    }
    gbar_arrive(bar, bid, s + 1);
  }
}

// ============== dec 8-wave variant (private helpers, runtime-gated) =========
__device__ __forceinline__ void d8_stage(_Float16* WF,
    const _Float16* W1, long st1, int K1,
    const _Float16* W2, long st2, int K2, int jh0, int tid) {
  const int n8 = ((K1 + K2) >> 5) * 64;
  for (int idx = tid; idx < n8; idx += 512) {
    const int q = idx >> 6, l = idx & 63;
    const int c = l & 15, qd = l >> 4;
    const int j = (c >> 2) * 512 + jh0 + (c & 3);
    const int k = q * 32 + qd * 8;
    const _Float16* src = (k < K1) ? (W1 + (long)j * st1 + k)
                                   : (W2 + (long)j * st2 + (k - K1));
    *(half8*)(WF + (long)idx * 8) = *(const half8*)src;
  }
}
template <int NQ>
__device__ __forceinline__ void d8_mm_norm(float4v (&acc)[2], const _Float16* WF,
                                           const _Float16* A, int mt0, int kq0, int lane) {
  const _Float16* wl = WF + lane * 8;
  const _Float16* ab = A + (long)mt0 * 512 + lane * 8;
  #pragma unroll
  for (int qq = 0; qq < NQ; ++qq) {
    const half8 bf = *(const half8*)(wl + (long)(kq0 + qq) * 512);
    const half8 af = *(const half8*)(ab + (long)qq * 4096);
    acc[(kq0 + qq) & 1] =
        __builtin_amdgcn_mfma_f32_16x16x32_f16(af, bf, acc[(kq0 + qq) & 1], 0, 0, 0);
  }
}
template <int NQ>
__device__ __forceinline__ void d8_mm_coh(float4v (&acc)[2], const _Float16* WF,
                                          const _Float16* A, int mt0, int kq0, int lane) {
  const _Float16* wl = WF + lane * 8;
  const _Float16* ab = A + (long)mt0 * 512 + lane * 8;
  #pragma unroll
  for (int qq = 0; qq < NQ; ++qq) {
    const half8 bf = *(const half8*)(wl + (long)(kq0 + qq) * 512);
    const half8 af = ld_h8c(ab + (long)qq * 4096);
    acc[(kq0 + qq) & 1] =
        __builtin_amdgcn_mfma_f32_16x16x32_f16(af, bf, acc[(kq0 + qq) & 1], 0, 0, 0);
  }
}
__device__ __forceinline__ void d8_cell(float4v (&acc)[2], int mt0, int jh0,
    float* c_reg, const float* b4, _Float16* hdst, int lane) {
  const int quad = lane >> 4, jl = lane & 3;
  const bool wr = (lane & 12) == 0;
  const int sbase = (lane & 48) | jl;
  #pragma unroll
  for (int r = 0; r < 4; ++r) {
    const float v = acc[0][r] + acc[1][r];
    const float iv = __shfl(v, sbase);
    const float fv = __shfl(v, sbase | 4);
    const float gv = __shfl(v, sbase | 8);
    const float ov = __shfl(v, sbase | 12);
    float h2 = 0.f;
    if (wr) {
      const float ig = iv + b4[0], fg = fv + b4[1], gg = gv + b4[2], og = ov + b4[3];
      const float si = 1.f / (1.f + __expf(-ig));
      const float sf = 1.f / (1.f + __expf(-fg));
      const float so = 1.f / (1.f + __expf(-og));
      const float eg = __expf(2.f * gg);
      const float tg = (eg - 1.f) / (eg + 1.f);
      const float c2 = sf * c_reg[r] + si * tg;
      c_reg[r] = c2;
      const float ec = __expf(2.f * c2);
      h2 = so * (ec - 1.f) / (ec + 1.f);
    }
    union { _Float16 f; unsigned short s; } hb; hb.f = (_Float16)h2;
    int b0 = (int)hb.s;
    int b1 = __shfl_xor(b0, 1);
    int lo = (b0 & 0xffff) | (b1 << 16);
    int hi = __shfl_xor(lo, 2);
    if ((lane & 15) == 0) {
      const unsigned long long u =
          (unsigned long long)(unsigned)lo | ((unsigned long long)(unsigned)hi << 32);
      const int m = mt0 * 16 + quad * 4 + r;
      st_u64c((unsigned long long*)(hdst + fragAddr(m, jh0)), u);
    }
  }
}

__launch_bounds__(512, 4)
__global__ void dec_persist8(PP P, unsigned int* bar) {
  const int bid = blockIdx.x, tid = threadIdx.x;
  const int wave = tid >> 6, lane = tid & 63, quad = lane >> 4;
  __shared__ _Float16 WF[24576];
  const int q = bid >> 7;              // 0=l0f 1=l0b 2=l1f 3=l1b
  const int layer = q >> 1, dir = q & 1;
  const int rsw = bid & 127;
  const int nidx = (rsw & 7) * 16 + (rsw >> 3);
  const int jh0 = nidx * 4, jh = jh0 + (lane & 3);
  const int mt0 = wave;                // 8 waves, one 16-row m-tile each
  const int slot = 4 + layer * 2 + dir;
  const int ld = layer * 2 + dir;

  if (layer == 0)
    d8_stage(WF, P.dw0 + (long)dir * G4 * C_IN, C_IN, C_IN,
                 P.dwh + (long)dir * G4 * H_SZ, H_SZ, H_SZ, jh0, tid);
  else
    d8_stage(WF, P.dwr + (long)dir * G4 * 1024, 1024, 1024,
                 P.dwh + (long)ld * G4 * H_SZ, H_SZ, H_SZ, jh0, tid);
  __syncthreads();
  float b4[4], c_reg[4];
  #pragma unroll
  for (int g = 0; g < 4; ++g) b4[g] = P.bcomb[(long)slot * G4 + g * 512 + jh];
  #pragma unroll
  for (int r = 0; r < 4; ++r)
    c_reg[r] = P.cst[(long)ld * HSLICE + (long)(mt0 * 16 + quad * 4 + r) * H_SZ + jh];

  for (int s = 0; s <= T_LEN; ++s) {
    const int p = s & 1;
    float4v acc[2] = {};
    if (layer == 0 && s < T_LEN)
      d8_mm_norm<4>(acc, WF, P.xF + (long)s * XFT, mt0, 0, lane);    // overlap zone
    gbar_wait(bar, bid, s);
    if (layer == 0) {
      if (s < T_LEN) {
        d8_mm_coh<16>(acc, WF, P.hst + (long)p * HPAR + (long)dir * HSLICE, mt0, 4, lane);
        d8_cell(acc, mt0, jh0, c_reg, b4,
                P.hst + (long)(1 - p) * HPAR + (long)dir * HSLICE, lane);
      }
    } else {
      if (s == 0) {
        if (tid < 64) {
          const long off = (long)(2 + dir) * HSLICE + ((long)rsw * 64 + tid) * 8;
          const unsigned long long* src = (const unsigned long long*)(P.hst + off);
          st_u64c((unsigned long long*)(P.hst + HPAR + off),     src[0]);
          st_u64c((unsigned long long*)(P.hst + HPAR + off) + 1, src[1]);
        }
      } else {
        d8_mm_coh<16>(acc, WF, P.hst + (long)p * HPAR + 0 * HSLICE, mt0, 0, lane);
        d8_mm_coh<16>(acc, WF, P.hst + (long)p * HPAR + 1 * HSLICE, mt0, 16, lane);
        d8_mm_coh<16>(acc, WF, P.hst + (long)p * HPAR + (long)(2 + dir) * HSLICE, mt0, 32, lane);
        d8_cell(acc, mt0, jh0, c_reg, b4,
                P.hst + (long)(1 - p) * HPAR + (long)(2 + dir) * HSLICE, lane);
      }
    }
    gbar_arrive(bar, bid, s + 1);
  }
}

// ============== dec NT=2 variant (private helpers, 256 blocks, dyn LDS) =====
// 16 blocks per leaf (256 blocks total).
__device__ __forceinline__ void g2_arrive(unsigned int* bar, int bid, unsigned g) {
  __syncthreads();
  if (threadIdx.x == 0) {
    unsigned old = __hip_atomic_fetch_add(bar + (bid & 15) * 16, 1u, __ATOMIC_RELAXED, SCOPE);
    if (old + 1 == 16u * g) {
      unsigned ro = __hip_atomic_fetch_add(bar + 256, 1u, __ATOMIC_RELAXED, SCOPE);
      if (ro + 1 == 16u * g) {
        #pragma unroll
        for (int i = 0; i < 8; ++i)
          __hip_atomic_store(bar + 320 + i * 16, g, __ATOMIC_RELAXED, SCOPE);
      }
    }
  }
}
__device__ __forceinline__ void g2_wait(unsigned int* bar, int bid, unsigned g) {
  if (g && threadIdx.x == 0) {
    while (__hip_atomic_load(bar + 320 + (bid & 7) * 16, __ATOMIC_RELAXED, SCOPE) < g)
      __builtin_amdgcn_s_sleep(2);
  }
  __syncthreads();
  asm volatile("" ::: "memory");
}

__device__ __forceinline__ void d2_stage(_Float16* WF,
    const _Float16* W1, long st1, int K1,
    const _Float16* W2, long st2, int K2, int jh0, int tid) {
  const int n8 = ((K1 + K2) >> 5) * 64;
  for (int idx = tid; idx < n8; idx += 512) {
    const int q = idx >> 6, l = idx & 63;
    const int c = l & 15, qd = l >> 4;
    const int j = (c >> 2) * 512 + jh0 + (c & 3);
    const int k = q * 32 + qd * 8;
    const _Float16* src = (k < K1) ? (W1 + (long)j * st1 + k)
                                   : (W2 + (long)j * st2 + (k - K1));
    *(half8*)(WF + (long)idx * 8) = *(const half8*)src;
  }
}
// A shared across two n-tiles: one A load feeds two MFMAs.
template <int NQ>
__device__ __forceinline__ void d2_mm_norm(float4v (&acc)[2][2], const _Float16* W0,
    const _Float16* W1, const _Float16* A, int mt0, int kq0, int lane) {
  const _Float16* wl0 = W0 + lane * 8;
  const _Float16* wl1 = W1 + lane * 8;
  const _Float16* ab = A + (long)mt0 * 512 + lane * 8;
  #pragma unroll
  for (int qq = 0; qq < NQ; ++qq) {
    const half8 af = *(const half8*)(ab + (long)qq * 4096);
    const int par = (kq0 + qq) & 1;
    acc[0][par] = __builtin_amdgcn_mfma_f32_16x16x32_f16(
        af, *(const half8*)(wl0 + (long)(kq0 + qq) * 512), acc[0][par], 0, 0, 0);
    acc[1][par] = __builtin_amdgcn_mfma_f32_16x16x32_f16(
        af, *(const half8*)(wl1 + (long)(kq0 + qq) * 512), acc[1][par], 0, 0, 0);
  }
}
template <int NQ>
__device__ __forceinline__ void d2_mm_coh(float4v (&acc)[2][2], const _Float16* W0,
    const _Float16* W1, const _Float16* A, int mt0, int kq0, int lane) {
  const _Float16* wl0 = W0 + lane * 8;
  const _Float16* wl1 = W1 + lane * 8;
  const _Float16* ab = A + (long)mt0 * 512 + lane * 8;
  #pragma unroll
  for (int qq = 0; qq < NQ; ++qq) {
    const half8 af = ld_h8c(ab + (long)qq * 4096);
    const int par = (kq0 + qq) & 1;
    acc[0][par] = __builtin_amdgcn_mfma_f32_16x16x32_f16(
        af, *(const half8*)(wl0 + (long)(kq0 + qq) * 512), acc[0][par], 0, 0, 0);
    acc[1][par] = __builtin_amdgcn_mfma_f32_16x16x32_f16(
        af, *(const half8*)(wl1 + (long)(kq0 + qq) * 512), acc[1][par], 0, 0, 0);
  }
}
// l1: 3 slices interleaved per k-chunk -> 3 independent coherent loads in flight.
__device__ __forceinline__ void d2_l1_mm(float4v (&acc)[2][2], const _Float16* W0,
    const _Float16* W1, const _Float16* A0, const _Float16* A1, const _Float16* A2,
    int mt0, int lane) {
  const _Float16* wl0 = W0 + lane * 8;
  const _Float16* wl1 = W1 + lane * 8;
  const long mo = (long)mt0 * 512 + lane * 8;
  const _Float16* ab0 = A0 + mo;
  const _Float16* ab1 = A1 + mo;
  const _Float16* ab2 = A2 + mo;
  #pragma unroll
  for (int qq = 0; qq < 16; ++qq) {
    const half8 af0 = ld_h8c(ab0 + (long)qq * 4096);
    const half8 af1 = ld_h8c(ab1 + (long)qq * 4096);
    const half8 af2 = ld_h8c(ab2 + (long)qq * 4096);
    const int par = qq & 1;
    acc[0][par] = __builtin_amdgcn_mfma_f32_16x16x32_f16(
        af0, *(const half8*)(wl0 + (long)qq * 512), acc[0][par], 0, 0, 0);
    acc[0][par] = __builtin_amdgcn_mfma_f32_16x16x32_f16(
        af1, *(const half8*)(wl0 + (long)(16 + qq) * 512), acc[0][par], 0, 0, 0);
    acc[0][par] = __builtin_amdgcn_mfma_f32_16x16x32_f16(
        af2, *(const half8*)(wl0 + (long)(32 + qq) * 512), acc[0][par], 0, 0, 0);
    acc[1][par] = __builtin_amdgcn_mfma_f32_16x16x32_f16(
        af0, *(const half8*)(wl1 + (long)qq * 512), acc[1][par], 0, 0, 0);
    acc[1][par] = __builtin_amdgcn_mfma_f32_16x16x32_f16(
        af1, *(const half8*)(wl1 + (long)(16 + qq) * 512), acc[1][par], 0, 0, 0);
    acc[1][par] = __builtin_amdgcn_mfma_f32_16x16x32_f16(
        af2, *(const half8*)(wl1 + (long)(32 + qq) * 512), acc[1][par], 0, 0, 0);
  }
}
__device__ __forceinline__ void d2_cell(float4v (&acc)[2][2], int mt0, int jhA, int jhB,
    float (&c_reg)[2][4], const float (&b4)[2][4], _Float16* hdst, int lane) {
  const int quad = lane >> 4;
  const bool wr = (lane & 12) == 0;
  const int sbase = (lane & 48) | (lane & 3);
  #pragma unroll
  for (int n = 0; n < 2; ++n) {
    const int jh0 = n ? jhB : jhA;
    #pragma unroll
    for (int r = 0; r < 4; ++r) {
      const float v = acc[n][0][r] + acc[n][1][r];
      const float iv = __shfl(v, sbase);
      const float fv = __shfl(v, sbase | 4);
      const float gv = __shfl(v, sbase | 8);
      const float ov = __shfl(v, sbase | 12);
      float h2 = 0.f;
      if (wr) {
        const float ig = iv + b4[n][0], fg = fv + b4[n][1];
        const float gg = gv + b4[n][2], og = ov + b4[n][3];
        const float si = 1.f / (1.f + __expf(-ig));
        const float sf = 1.f / (1.f + __expf(-fg));
        const float so = 1.f / (1.f + __expf(-og));
        const float eg = __expf(2.f * gg);
        const float tg = (eg - 1.f) / (eg + 1.f);
        const float c2 = sf * c_reg[n][r] + si * tg;
        c_reg[n][r] = c2;
        const float ec = __expf(2.f * c2);
        h2 = so * (ec - 1.f) / (ec + 1.f);
      }
      union { _Float16 f; unsigned short s; } hb; hb.f = (_Float16)h2;
      int b0 = (int)hb.s;
      int b1 = __shfl_xor(b0, 1);
      int lo = (b0 & 0xffff) | (b1 << 16);
      int hi = __shfl_xor(lo, 2);
      if ((lane & 15) == 0) {
        const unsigned long long u =
            (unsigned long long)(unsigned)lo | ((unsigned long long)(unsigned)hi << 32);
        const int m = mt0 * 16 + quad * 4 + r;
        st_u64c((unsigned long long*)(hdst + fragAddr(m, jh0)), u);
      }
    }
  }
}

__launch_bounds__(512, 2)
__global__ void dec_persist_nt2(PP P, unsigned int* bar) {
  extern __shared__ _Float16 WFD[];
  const int bid = blockIdx.x, tid = threadIdx.x;
  const int wave = tid >> 6, lane = tid & 63, quad = lane >> 4, jl = lane & 3;
  const int q = bid >> 6;              // 256 blocks: 0=l0f 1=l0b 2=l1f 3=l1b
  const int layer = q >> 1, dir = q & 1;
  const int cg = bid & 63;
  const int sw = (cg & 7) * 8 + (cg >> 3);  // bijective 0..63 spread
  const int jhA = sw * 4, jhB = (sw + 64) * 4;
  const int mt0 = wave;                // 8 waves, one 16-row m-tile each
  const int slot = 4 + layer * 2 + dir;
  const int ld = layer * 2 + dir;
  const int kqt = (layer == 0) ? 20 : 48;
  _Float16* W0 = WFD;
  _Float16* W1 = WFD + (long)kqt * 512;

  if (layer == 0) {
    d2_stage(W0, P.dw0 + (long)dir * G4 * C_IN, C_IN, C_IN,
                 P.dwh + (long)dir * G4 * H_SZ, H_SZ, H_SZ, jhA, tid);
    d2_stage(W1, P.dw0 + (long)dir * G4 * C_IN, C_IN, C_IN,
                 P.dwh + (long)dir * G4 * H_SZ, H_SZ, H_SZ, jhB, tid);
  } else {
    d2_stage(W0, P.dwr + (long)dir * G4 * 1024, 1024, 1024,
                 P.dwh + (long)ld * G4 * H_SZ, H_SZ, H_SZ, jhA, tid);
    d2_stage(W1, P.dwr + (long)dir * G4 * 1024, 1024, 1024,
                 P.dwh + (long)ld * G4 * H_SZ, H_SZ, H_SZ, jhB, tid);
  }
  __syncthreads();
  float b4[2][4], c_reg[2][4];
  #pragma unroll
  for (int n = 0; n < 2; ++n) {
    const int jh = (n ? jhB : jhA) + jl;
    #pragma unroll
    for (int g = 0; g < 4; ++g) b4[n][g] = P.bcomb[(long)slot * G4 + g * 512 + jh];
    #pragma unroll
    for (int r = 0; r < 4; ++r)
      c_reg[n][r] = P.cst[(long)ld * HSLICE + (long)(mt0 * 16 + quad * 4 + r) * H_SZ + jh];
  }

  for (int s = 0; s <= T_LEN; ++s) {
    const int p = s & 1;
    float4v acc[2][2] = {};
    if (layer == 0 && s < T_LEN)
      d2_mm_norm<4>(acc, W0, W1, P.xF + (long)s * XFT, mt0, 0, lane); // overlap zone
    g2_wait(bar, bid, s);
    if (layer == 0) {
      if (s < T_LEN) {
        d2_mm_coh<16>(acc, W0, W1, P.hst + (long)p * HPAR + (long)dir * HSLICE, mt0, 4, lane);
        d2_cell(acc, mt0, jhA, jhB, c_reg, b4,
                P.hst + (long)(1 - p) * HPAR + (long)dir * HSLICE, lane);
      }
    } else {
      if (s == 0) {
        // seed own h into parity 1 (step s=1 reads parity 1); src from enc1 final.
        const int idx = cg * 512 + tid;
        if (idx < 16384) {
          const long soff = (long)(2 + dir) * HSLICE;
          const unsigned long long* src = (const unsigned long long*)(P.hst + soff);
          st_u64c((unsigned long long*)(P.hst + HPAR + soff) + idx, src[idx]);
        }
      } else {
        const _Float16* base = P.hst + (long)p * HPAR;
        d2_l1_mm(acc, W0, W1, base, base + HSLICE, base + (long)(2 + dir) * HSLICE,
                 mt0, lane);
        d2_cell(acc, mt0, jhA, jhB, c_reg, b4,
                P.hst + (long)(1 - p) * HPAR + (long)(2 + dir) * HSLICE, lane);
      }
    }
    g2_arrive(bar, bid, s + 1);
  }
}

// ============== dec NT=2 PIPELINED variant (round 9, private mm helpers) ====
// Same geometry/barrier as dec_persist_nt2; only the coherent-load loops are
// explicitly software-pipelined (depth-4 l0, depth-2x3 l1) to raise MLP.
template <int NQ>
__device__ __forceinline__ void p2_mm_coh(float4v (&acc)[2][2], const _Float16* W0,
    const _Float16* W1, const _Float16* A, int mt0, int kq0, int lane) {
  const _Float16* wl0 = W0 + lane * 8;
  const _Float16* wl1 = W1 + lane * 8;
  const _Float16* ab = A + (long)mt0 * 512 + lane * 8;
  half8 buf[4];
  #pragma unroll
  for (int i = 0; i < 4; ++i) buf[i] = ld_h8c(ab + (long)i * 4096);
  #pragma unroll
  for (int qq = 0; qq < NQ; ++qq) {
    const half8 af = buf[qq & 3];
    if (qq + 4 < NQ) buf[qq & 3] = ld_h8c(ab + (long)(qq + 4) * 4096);
    const int par = (kq0 + qq) & 1;
    acc[0][par] = __builtin_amdgcn_mfma_f32_16x16x32_f16(
        af, *(const half8*)(wl0 + (long)(kq0 + qq) * 512), acc[0][par], 0, 0, 0);
    acc[1][par] = __builtin_amdgcn_mfma_f32_16x16x32_f16(
        af, *(const half8*)(wl1 + (long)(kq0 + qq) * 512), acc[1][par], 0, 0, 0);
  }
}
__device__ __forceinline__ void p2_l1_mm(float4v (&acc)[2][2], const _Float16* W0,
    const _Float16* W1, const _Float16* A0, const _Float16* A1, const _Float16* A2,
    int mt0, int lane) {
  const _Float16* wl0 = W0 + lane * 8;
  const _Float16* wl1 = W1 + lane * 8;
  const long mo = (long)mt0 * 512 + lane * 8;
  const _Float16* ab0 = A0 + mo;
  const _Float16* ab1 = A1 + mo;
  const _Float16* ab2 = A2 + mo;
  half8 c0 = ld_h8c(ab0), c1 = ld_h8c(ab1), c2 = ld_h8c(ab2);
  #pragma unroll
  for (int qq = 0; qq < 16; ++qq) {
    half8 n0, n1, n2;
    if (qq < 15) {
      n0 = ld_h8c(ab0 + (long)(qq + 1) * 4096);
      n1 = ld_h8c(ab1 + (long)(qq + 1) * 4096);
      n2 = ld_h8c(ab2 + (long)(qq + 1) * 4096);
    }
    const int par = qq & 1;
    acc[0][par] = __builtin_amdgcn_mfma_f32_16x16x32_f16(
        c0, *(const half8*)(wl0 + (long)qq * 512), acc[0][par], 0, 0, 0);
    acc[0][par] = __builtin_amdgcn_mfma_f32_16x16x32_f16(
        c1, *(const half8*)(wl0 + (long)(16 + qq) * 512), acc[0][par], 0, 0, 0);
    acc[0][par] = __builtin_amdgcn_mfma_f32_16x16x32_f16(
        c2, *(const half8*)(wl0 + (long)(32 + qq) * 512), acc[0][par], 0, 0, 0);
    acc[1][par] = __builtin_amdgcn_mfma_f32_16x16x32_f16(
        c0, *(const half8*)(wl1 + (long)qq * 512), acc[1][par], 0, 0, 0);
    acc[1][par] = __builtin_amdgcn_mfma_f32_16x16x32_f16(
        c1, *(const half8*)(wl1 + (long)(16 + qq) * 512), acc[1][par], 0, 0, 0);
    acc[1][par] = __builtin_amdgcn_mfma_f32_16x16x32_f16(
        c2, *(const half8*)(wl1 + (long)(32 + qq) * 512), acc[1][par], 0, 0, 0);
    if (qq < 15) { c0 = n0; c1 = n1; c2 = n2; }
  }
}

__launch_bounds__(512, 2)
__global__ void dec_nt2p(PP P, unsigned int* bar) {
  extern __shared__ _Float16 WFP[];
  const int bid = blockIdx.x, tid = threadIdx.x;
  const int wave = tid >> 6, lane = tid & 63, quad = lane >> 4, jl = lane & 3;
  const int q = bid >> 6;              // 256 blocks: 0=l0f 1=l0b 2=l1f 3=l1b
  const int layer = q >> 1, dir = q & 1;
  const int cg = bid & 63;
  const int sw = (cg & 7) * 8 + (cg >> 3);
  const int jhA = sw * 4, jhB = (sw + 64) * 4;
  const int mt0 = wave;
  const int slot = 4 + layer * 2 + dir;
  const int ld = layer * 2 + dir;
  const int kqt = (layer == 0) ? 20 : 48;
  _Float16* W0 = WFP;
  _Float16* W1 = WFP + (long)kqt * 512;

  if (layer == 0) {
    d2_stage(W0, P.dw0 + (long)dir * G4 * C_IN, C_IN, C_IN,
                 P.dwh + (long)dir * G4 * H_SZ, H_SZ, H_SZ, jhA, tid);
    d2_stage(W1, P.dw0 + (long)dir * G4 * C_IN, C_IN, C_IN,
                 P.dwh + (long)dir * G4 * H_SZ, H_SZ, H_SZ, jhB, tid);
  } else {
    d2_stage(W0, P.dwr + (long)dir * G4 * 1024, 1024, 1024,
                 P.dwh + (long)ld * G4 * H_SZ, H_SZ, H_SZ, jhA, tid);
    d2_stage(W1, P.dwr + (long)dir * G4 * 1024, 1024, 1024,
                 P.dwh + (long)ld * G4 * H_SZ, H_SZ, H_SZ, jhB, tid);
  }
  __syncthreads();
  float b4[2][4], c_reg[2][4];
  #pragma unroll
  for (int n = 0; n < 2; ++n) {
    const int jh = (n ? jhB : jhA) + jl;
    #pragma unroll
    for (int g = 0; g < 4; ++g) b4[n][g] = P.bcomb[(long)slot * G4 + g * 512 + jh];
    #pragma unroll
    for (int r = 0; r < 4; ++r)
      c_reg[n][r] = P.cst[(long)ld * HSLICE + (long)(mt0 * 16 + quad * 4 + r) * H_SZ + jh];
  }

  for (int s = 0; s <= T_LEN; ++s) {
    const int p = s & 1;
    float4v acc[2][2] = {};
    if (layer == 0 && s < T_LEN)
      d2_mm_norm<4>(acc, W0, W1, P.xF + (long)s * XFT, mt0, 0, lane); // overlap zone
    g2_wait(bar, bid, s);
    if (layer == 0) {
      if (s < T_LEN) {
        p2_mm_coh<16>(acc, W0, W1, P.hst + (long)p * HPAR + (long)dir * HSLICE, mt0, 4, lane);
        d2_cell(acc, mt0, jhA, jhB, c_reg, b4,
                P.hst + (long)(1 - p) * HPAR + (long)dir * HSLICE, lane);
      }
    } else {
      if (s == 0) {
        const int idx = cg * 512 + tid;
        if (idx < 16384) {
          const long soff = (long)(2 + dir) * HSLICE;
          const unsigned long long* src = (const unsigned long long*)(P.hst + soff);
          st_u64c((unsigned long long*)(P.hst + HPAR + soff) + idx, src[idx]);
        }
      } else {
        const _Float16* base = P.hst + (long)p * HPAR;
        p2_l1_mm(acc, W0, W1, base, base + HSLICE, base + (long)(2 + dir) * HSLICE,
                 mt0, lane);
        d2_cell(acc, mt0, jhA, jhB, c_reg, b4,
                P.hst + (long)(1 - p) * HPAR + (long)(2 + dir) * HSLICE, lane);
      }
    }
    g2_arrive(bar, bid, s + 1);
  }
}

// ============== enc PIPELINED variants (round 9, private helpers) ===========
// Identical geometry/barrier to enc0_persist/enc1_persist (512 blocks x 256);
// only the post-barrier coherent loop is depth-4 pipelined.
__device__ __forceinline__ void pl_stage(_Float16* WF,
    const _Float16* W1, long st1, int K1,
    const _Float16* W2, long st2, int K2, int jh0, int tid) {
  const int n8 = ((K1 + K2) >> 5) * 64;
  for (int idx = tid; idx < n8; idx += 256) {
    const int q = idx >> 6, l = idx & 63;
    const int c = l & 15, qd = l >> 4;
    const int j = (c >> 2) * 512 + jh0 + (c & 3);
    const int k = q * 32 + qd * 8;
    const _Float16* src = (k < K1) ? (W1 + (long)j * st1 + k)
                                   : (W2 + (long)j * st2 + (k - K1));
    *(half8*)(WF + (long)idx * 8) = *(const half8*)src;
  }
}
template <int NQ>
__device__ __forceinline__ void pl_mm_norm(float4v (&acc)[2], const _Float16* WF,
                                           const _Float16* A, int mt0, int kq0, int lane) {
  const _Float16* wl = WF + lane * 8;
  const _Float16* ab = A + (long)mt0 * 512 + lane * 8;
  #pragma unroll
  for (int qq = 0; qq < NQ; ++qq) {
    const half8 bf = *(const half8*)(wl + (long)(kq0 + qq) * 512);
    const half8 af = *(const half8*)(ab + (long)qq * 4096);
    acc[(kq0 + qq) & 1] =
        __builtin_amdgcn_mfma_f32_16x16x32_f16(af, bf, acc[(kq0 + qq) & 1], 0, 0, 0);
  }
}
template <int NQ>
__device__ __forceinline__ void pl_mm_coh(float4v (&acc)[2], const _Float16* WF,
                                          const _Float16* A, int mt0, int kq0, int lane) {
  const _Float16* wl = WF + lane * 8;
  const _Float16* ab = A + (long)mt0 * 512 + lane * 8;
  half8 buf[4];
  #pragma unroll
  for (int i = 0; i < 4; ++i) buf[i] = ld_h8c(ab + (long)i * 4096);
  #pragma unroll
  for (int qq = 0; qq < NQ; ++qq) {
    const half8 af = buf[qq & 3];
    if (qq + 4 < NQ) buf[qq & 3] = ld_h8c(ab + (long)(qq + 4) * 4096);
    const half8 bf = *(const half8*)(wl + (long)(kq0 + qq) * 512);
    acc[(kq0 + qq) & 1] =
        __builtin_amdgcn_mfma_f32_16x16x32_f16(af, bf, acc[(kq0 + qq) & 1], 0, 0, 0);
  }
}
__device__ __forceinline__ void pl_cell(float4v (&acc)[2], int mt0, int jh0,
    float* c_reg, const float* b4, _Float16* hdst, _Float16* ydst, int ycol0, int lane) {
  const int quad = lane >> 4, jl = lane & 3;
  const bool wr = (lane & 12) == 0;
  const int sbase = (lane & 48) | jl;
  #pragma unroll
  for (int r = 0; r < 4; ++r) {
    const float v = acc[0][r] + acc[1][r];
    const float iv = __shfl(v, sbase);
    const float fv = __shfl(v, sbase | 4);
    const float gv = __shfl(v, sbase | 8);
    const float ov = __shfl(v, sbase | 12);
    float h2 = 0.f;
    if (wr) {
      const float ig = iv + b4[0], fg = fv + b4[1], gg = gv + b4[2], og = ov + b4[3];
      const float si = 1.f / (1.f + __expf(-ig));
      const float sf = 1.f / (1.f + __expf(-fg));
      const float so = 1.f / (1.f + __expf(-og));
      const float eg = __expf(2.f * gg);
      const float tg = (eg - 1.f) / (eg + 1.f);
      const float c2 = sf * c_reg[r] + si * tg;
      c_reg[r] = c2;
      const float ec = __expf(2.f * c2);
      h2 = so * (ec - 1.f) / (ec + 1.f);
    }
    union { _Float16 f; unsigned short s; } hb; hb.f = (_Float16)h2;
    int b0 = (int)hb.s;
    int b1 = __shfl_xor(b0, 1);
    int lo = (b0 & 0xffff) | (b1 << 16);
    int hi = __shfl_xor(lo, 2);
    if ((lane & 15) == 0) {
      const unsigned long long u =
          (unsigned long long)(unsigned)lo | ((unsigned long long)(unsigned)hi << 32);
      const int m = mt0 * 16 + quad * 4 + r;
      st_u64c((unsigned long long*)(hdst + fragAddr(m, jh0)), u);
      if (ydst) *(unsigned long long*)(ydst + fragAddr(m, ycol0)) = u;
    }
  }
}

__launch_bounds__(256, 2)
__global__ void enc0_pl(PP P, unsigned int* bar) {
  const int bid = blockIdx.x, tid = threadIdx.x;
  const int wave = tid >> 6, lane = tid & 63, quad = lane >> 4;
  __shared__ _Float16 WF[24576];
  const int dir = bid >> 8, mg = (bid >> 7) & 1, rsw = bid & 127;
  const int nidx = (rsw & 7) * 16 + (rsw >> 3);
  const int jh0 = nidx * 4, jh = jh0 + (lane & 3);
  const int mt0 = mg * 4 + wave;

  pl_stage(WF, P.ew0 + (long)dir * G4 * C_IN, C_IN, C_IN,
               P.ewh + (long)dir * G4 * H_SZ, H_SZ, H_SZ, jh0, tid);
  __syncthreads();
  float b4[4], c_reg[4];
  #pragma unroll
  for (int g = 0; g < 4; ++g) b4[g] = P.bcomb[(long)dir * G4 + g * 512 + jh];
  #pragma unroll
  for (int r = 0; r < 4; ++r)
    c_reg[r] = P.cst[(long)dir * HSLICE + (long)(mt0 * 16 + quad * 4 + r) * H_SZ + jh];

  for (int s = 0; s < T_LEN; ++s) {
    const int p = s & 1;
    const int td = dir ? (T_LEN - 1 - s) : s;
    float4v acc[2] = {};
    pl_mm_norm<4>(acc, WF, P.xF + (long)td * XFT, mt0, 0, lane);     // overlap zone
    gbar_wait(bar, bid, s);
    pl_mm_coh<16>(acc, WF, P.hst + (long)p * HPAR + (long)dir * HSLICE, mt0, 4, lane);
    pl_cell(acc, mt0, jh0, c_reg, b4,
            P.hst + (long)(1 - p) * HPAR + (long)dir * HSLICE,
            P.y0F + (long)td * Y0T, dir * 512 + jh0, lane);
    gbar_arrive(bar, bid, s + 1);
  }
  if ((lane & 12) == 0) {
    #pragma unroll
    for (int r = 0; r < 4; ++r)
      P.cst[(long)dir * HSLICE + (long)(mt0 * 16 + quad * 4 + r) * H_SZ + jh] = c_reg[r];
  }
}

__launch_bounds__(256, 2)
__global__ void enc1_pl(PP P, unsigned int* bar) {
  const int bid = blockIdx.x, tid = threadIdx.x;
  const int wave = tid >> 6, lane = tid & 63, quad = lane >> 4;
  __shared__ _Float16 WF[24576];
  const int dir = bid >> 8, mg = (bid >> 7) & 1, rsw = bid & 127;
  const int nidx = (rsw & 7) * 16 + (rsw >> 3);
  const int jh0 = nidx * 4, jh = jh0 + (lane & 3);
  const int mt0 = mg * 4 + wave;
  const int ld = 2 + dir;

  pl_stage(WF, P.ewr + (long)dir * G4 * 1024, 1024, 1024,
               P.ewh + (long)ld * G4 * H_SZ, H_SZ, H_SZ, jh0, tid);
  __syncthreads();
  float b4[4], c_reg[4];
  #pragma unroll
  for (int g = 0; g < 4; ++g) b4[g] = P.bcomb[(long)ld * G4 + g * 512 + jh];
  #pragma unroll
  for (int r = 0; r < 4; ++r)
    c_reg[r] = P.cst[(long)ld * HSLICE + (long)(mt0 * 16 + quad * 4 + r) * H_SZ + jh];

  for (int s = 0; s < T_LEN; ++s) {
    const int p = s & 1;
    const int td = dir ? (T_LEN - 1 - s) : s;
    float4v acc[2] = {};
    pl_mm_norm<32>(acc, WF, P.y0F + (long)td * Y0T, mt0, 0, lane);   // overlap zone
    gbar_wait(bar, bid, s);
    pl_mm_coh<16>(acc, WF, P.hst + (long)p * HPAR + (long)ld * HSLICE, mt0, 32, lane);
    pl_cell(acc, mt0, jh0, c_reg, b4,
            P.hst + (long)(1 - p) * HPAR + (long)ld * HSLICE, nullptr, 0, lane);
    gbar_arrive(bar, bid, s + 1);
  }
  if ((lane & 12) == 0) {
    #pragma unroll
    for (int r = 0; r < 4; ++r)
      P.cst[(long)ld * HSLICE + (long)(mt0 * 16 + quad * 4 + r) * H_SZ + jh] = c_reg[r];
  }
}

// ---------------------------------------------------------------------------
__global__ void f2h(const float* __restrict__ src, _Float16* __restrict__ dst, long n) {
  for (long i = blockIdx.x * 256L + threadIdx.x; i < n; i += (long)gridDim.x * 256)
    dst[i] = (_Float16)src[i];
}

__global__ void x_to_frag(const float* __restrict__ x, _Float16* __restrict__ xF) {
  const int t = blockIdx.x, b = blockIdx.y, c = threadIdx.x;
  xF[(long)t * XFT + fragAddr(b, c)] = (_Float16)x[((long)b * T_LEN + t) * C_IN + c];
}

__global__ void h0_to_frag(const float* __restrict__ h0, _Float16* __restrict__ hstF) {
  const long i = blockIdx.x * 256L + threadIdx.x;
  const int ld = (int)(i >> 16);
  const int b = (int)((i >> 9) & 127);
  const int k = (int)(i & 511);
  hstF[(long)ld * HSLICE + fragAddr(b, k)] = (_Float16)h0[i];
}

__global__ void bias_combine(const float* __restrict__ e_bih, const float* __restrict__ e_bhh,
                             const float* __restrict__ d_bih, const float* __restrict__ d_bhh,
                             float* __restrict__ bcomb) {
  const int i = blockIdx.x * 256 + threadIdx.x;
  const int slot = i >> 11;
  const int j = i & 2047;
  float v;
  if (slot < 4) v = e_bih[slot * 2048 + j] + e_bhh[slot * 2048 + j];
  else          v = d_bih[(slot - 4) * 2048 + j] + d_bhh[(slot - 4) * 2048 + j];
  bcomb[i] = v;
}

__global__ void final_linear(const _Float16* __restrict__ hF,  // hst + HPAR
                             const float* __restrict__ lin_w, const float* __restrict__ lb,
                             float* __restrict__ out) {
  const int tid = threadIdx.x;
  const int o = tid & 127;
  const int b = blockIdx.x * 2 + (tid >> 7);
  const float* w = lin_w + (long)o * 1024;
  float acc = 0.f;
  for (int k = 0; k < H_SZ; ++k) acc += (float)hF[2L * HSLICE + fragAddr(b, k)] * w[k];
  for (int k = 0; k < H_SZ; ++k) acc += (float)hF[3L * HSLICE + fragAddr(b, k)] * w[H_SZ + k];
  out[(long)b * 128 + o] = acc + lb[o];
}

__global__ void fill_val(float* __restrict__ p, int n, float v) {
  const int i = blockIdx.x * 256 + threadIdx.x;
  if (i < n) p[i] = v;
}

// ---------------------------------------------------------------------------
extern "C" void kernel_launch(void* const* d_in, const int* in_sizes, int n_in,
                              void* d_out, int out_size, void* d_ws, size_t ws_size,
                              hipStream_t stream) {
  (void)in_sizes; (void)n_in;
  const float* x      = (const float*)d_in[0];
  const float* h0     = (const float*)d_in[1];
  const float* c0     = (const float*)d_in[2];
  const float* e_wih0 = (const float*)d_in[3];
  const float* e_wihr = (const float*)d_in[4];
  const float* e_whh  = (const float*)d_in[5];
  const float* e_bih  = (const float*)d_in[6];
  const float* e_bhh  = (const float*)d_in[7];
  const float* dw_ih0 = (const float*)d_in[8];
  const float* dw_ihr = (const float*)d_in[9];
  const float* dw_hh  = (const float*)d_in[10];
  const float* db_ih  = (const float*)d_in[11];
  const float* db_hh  = (const float*)d_in[12];
  const float* lin_w  = (const float*)d_in[13];
  const float* lin_b  = (const float*)d_in[14];
  float* out = (float*)d_out;

  char* wsb = (char*)d_ws;
  size_t off = 0;
  auto carve = [&](size_t bytes) -> void* {
    void* pp = wsb + off;
    off += (bytes + 255) & ~(size_t)255;
    return pp;
  };
  _Float16* xF  = (_Float16*)carve((size_t)T_LEN * XFT * 2);
  _Float16* ew0 = (_Float16*)carve(2L * G4 * C_IN * 2);
  _Float16* ewr = (_Float16*)carve(2L * G4 * 1024 * 2);
  _Float16* ewh = (_Float16*)carve(4L * G4 * H_SZ * 2);
  _Float16* dw0 = (_Float16*)carve(2L * G4 * C_IN * 2);
  _Float16* dwr = (_Float16*)carve(2L * G4 * 1024 * 2);
  _Float16* dwh = (_Float16*)carve(4L * G4 * H_SZ * 2);
  _Float16* y0F = (_Float16*)carve((size_t)T_LEN * Y0T * 2);
  float* bcomb  = (float*)carve(8L * G4 * 4);
  _Float16* hst = (_Float16*)carve(2L * HPAR * 2);
  float* cst    = (float*)carve(4L * HSLICE * 4);
  unsigned int* bar0 = (unsigned int*)carve(2048);
  unsigned int* bar1 = (unsigned int*)carve(2048);
  unsigned int* bar2 = (unsigned int*)carve(2048);

  if (off > ws_size) {
    hipMemsetAsync(d_out, 0, (size_t)out_size * 4, stream);
    return;
  }

  // ---- prep ----
  hipMemsetAsync(bar0, 0, 3 * 2048, stream);
  x_to_frag<<<dim3(T_LEN, B_SZ), C_IN, 0, stream>>>(x, xF);
  f2h<<<64,  256, 0, stream>>>(e_wih0, ew0, 2L * G4 * C_IN);
  f2h<<<256, 256, 0, stream>>>(e_wihr, ewr, 2L * G4 * 1024);
  f2h<<<256, 256, 0, stream>>>(e_whh,  ewh, 4L * G4 * H_SZ);
  f2h<<<64,  256, 0, stream>>>(dw_ih0, dw0, 2L * G4 * C_IN);
  f2h<<<256, 256, 0, stream>>>(dw_ihr, dwr, 2L * G4 * 1024);
  f2h<<<256, 256, 0, stream>>>(dw_hh,  dwh, 4L * G4 * H_SZ);
  h0_to_frag<<<1024, 256, 0, stream>>>(h0, hst);
  bias_combine<<<64, 256, 0, stream>>>(e_bih, e_bhh, db_ih, db_hh, bcomb);
  hipMemcpyAsync(cst, c0, 4L * HSLICE * 4, hipMemcpyDeviceToDevice, stream);

  // ---- variant gates ----
  int use_e0p = 0;
  {
    int mab = 0;
    if (hipOccupancyMaxActiveBlocksPerMultiprocessor(&mab, enc0_pl, 256, 0) == hipSuccess
        && mab >= 2)
      use_e0p = 1;
  }
  int use_e1p = 0;
  {
    int mab = 0;
    if (hipOccupancyMaxActiveBlocksPerMultiprocessor(&mab, enc1_pl, 256, 0) == hipSuccess
        && mab >= 2)
      use_e1p = 1;
  }
  int use_dp = 0;
  if (hipFuncSetAttribute(reinterpret_cast<const void*>(dec_nt2p),
                          hipFuncAttributeMaxDynamicSharedMemorySize, 98304) == hipSuccess) {
    int mab = 0;
    if (hipOccupancyMaxActiveBlocksPerMultiprocessor(&mab, dec_nt2p, 512, 98304)
            == hipSuccess && mab >= 1)
      use_dp = 1;
  }
  int use_nt2 = 0;
  if (hipFuncSetAttribute(reinterpret_cast<const void*>(dec_persist_nt2),
                          hipFuncAttributeMaxDynamicSharedMemorySize, 98304) == hipSuccess) {
    int mab = 0;
    if (hipOccupancyMaxActiveBlocksPerMultiprocessor(&mab, dec_persist_nt2, 512, 98304)
            == hipSuccess && mab >= 1)
      use_nt2 = 1;
  }
  int mab8 = 0;
  if (hipOccupancyMaxActiveBlocksPerMultiprocessor(&mab8, dec_persist8, 512, 0) != hipSuccess)
    mab8 = 0;

  // ---- three persistent cooperative kernels (split-phase barriers) ----
  PP P{ xF, ew0, ewr, ewh, dw0, dwr, dwh, bcomb, y0F, hst, cst };
  hipError_t e;
  {
    void* a0[] = { &P, &bar0 };
    e = hipErrorUnknown;
    if (use_e0p)
      e = hipLaunchCooperativeKernel((void*)enc0_pl, dim3(512), dim3(256), a0, 0, stream);
    if (e != hipSuccess)
      e = hipLaunchCooperativeKernel((void*)enc0_persist, dim3(512), dim3(256), a0, 0, stream);
    if (e != hipSuccess) { fill_val<<<64, 256, 0, stream>>>(out, 16384, 1.0e4f); return; }
  }
  {
    void* a1[] = { &P, &bar1 };
    e = hipErrorUnknown;
    if (use_e1p)
      e = hipLaunchCooperativeKernel((void*)enc1_pl, dim3(512), dim3(256), a1, 0, stream);
    if (e != hipSuccess)
      e = hipLaunchCooperativeKernel((void*)enc1_persist, dim3(512), dim3(256), a1, 0, stream);
    if (e != hipSuccess) { fill_val<<<64, 256, 0, stream>>>(out, 16384, 2.0e4f); return; }
  }
  {
    void* a2[] = { &P, &bar2 };
    e = hipErrorUnknown;
    if (use_dp)
      e = hipLaunchCooperativeKernel((void*)dec_nt2p, dim3(256), dim3(512), a2, 98304, stream);
    if (e != hipSuccess && use_nt2)
      e = hipLaunchCooperativeKernel((void*)dec_persist_nt2, dim3(256), dim3(512), a2,
                                     98304, stream);
    if (e != hipSuccess) {
      if (mab8 >= 2)
        e = hipLaunchCooperativeKernel((void*)dec_persist8, dim3(512), dim3(512), a2, 0, stream);
      else
        e = hipLaunchCooperativeKernel((void*)dec_persist, dim3(512), dim3(256), a2, 0, stream);
    }
    if (e != hipSuccess) { fill_val<<<64, 256, 0, stream>>>(out, 16384, 4.0e4f); return; }
  }

  // ---- final linear on decoder l1 t=511 output (parity 1, ld 2/3) ----
  final_linear<<<64, 256, 0, stream>>>(hst + HPAR, lin_w, lin_b, out);
}